// Round 3
// baseline (1595.430 us; speedup 1.0000x reference)
//
#include <hip/hip_runtime.h>
#include <math.h>

#define D   128
#define H   4
#define PP  5
#define DT  32
#define FF  512
#define NL  2
#define SCALE 0.08838834764831845f

__device__ __forceinline__ float gelu(float x) {
    return 0.5f * x * (1.0f + erff(x * 0.7071067811865476f));
}

// ---------------------------------------------------------------------------
// dist_attn table: 8 possible pf vectors -> gelu(pf@dW1+db1)@dW2+db2  (8 x H)
// rows 0..5 = path_len_emb[plen], 6 = vp_emb, 7 = sl_emb
// ---------------------------------------------------------------------------
__global__ __launch_bounds__(256) void k_dist_tab(
    const float* __restrict__ ple, const float* __restrict__ vpe, const float* __restrict__ sle,
    const float* __restrict__ dW1, const float* __restrict__ db1,
    const float* __restrict__ dW2, const float* __restrict__ db2,
    float* __restrict__ dist_tab)
{
    __shared__ float pf[8][D];
    __shared__ float hid[8][D];
    int t = threadIdx.x;
    for (int i = t; i < 8 * D; i += 256) {
        int r = i >> 7, c = i & 127;
        float v;
        if (r < 6)      v = ple[r * D + c];
        else if (r == 6) v = vpe[c];
        else             v = sle[c];
        pf[r][c] = v;
    }
    __syncthreads();
    for (int i = t; i < 8 * D; i += 256) {
        int r = i >> 7, c = i & 127;
        float s = db1[c];
        for (int k = 0; k < D; ++k) s += pf[r][k] * dW1[k * D + c];
        hid[r][c] = gelu(s);
    }
    __syncthreads();
    if (t < 8 * H) {
        int r = t >> 2, h = t & 3;
        float s = db2[h];
        for (int k = 0; k < D; ++k) s += hid[r][k] * dW2[k * H + h];
        dist_tab[r * H + h] = s;
    }
}

// ---------------------------------------------------------------------------
// tab[i][n][:] = gelu(X[n]@tWin[i]+tbin[i]) @ tWout[i] + tbout[i]
// block: 64 nodes, 256 threads
// ---------------------------------------------------------------------------
__global__ __launch_bounds__(256) void k_tab(
    const float* __restrict__ X, const float* __restrict__ tWin, const float* __restrict__ tbin,
    const float* __restrict__ tWout, const float* __restrict__ tbout,
    float* __restrict__ tab, int N)
{
    __shared__ float Xs[64][D];
    __shared__ float Hs[64][DT];
    int t = threadIdx.x;
    int n0 = blockIdx.x * 64;
    int nrows = N - n0; if (nrows > 64) nrows = 64;
    for (int i = t; i < 64 * D; i += 256) {
        int r = i >> 7, c = i & 127;
        Xs[r][c] = (r < nrows) ? X[(size_t)(n0 + r) * D + c] : 0.0f;
    }
    int col = t & 31;
    int rg  = t >> 5;
    __syncthreads();
    for (int i = 0; i < PP; ++i) {
        const float* Wi = tWin + (size_t)i * D * DT;
        float acc[8];
        float b = tbin[i * DT + col];
#pragma unroll
        for (int j = 0; j < 8; ++j) acc[j] = b;
        for (int k4 = 0; k4 < D / 4; ++k4) {
            float w0 = Wi[(k4 * 4 + 0) * DT + col];
            float w1 = Wi[(k4 * 4 + 1) * DT + col];
            float w2 = Wi[(k4 * 4 + 2) * DT + col];
            float w3 = Wi[(k4 * 4 + 3) * DT + col];
#pragma unroll
            for (int j = 0; j < 8; ++j) {
                float4 x = *(const float4*)&Xs[rg * 8 + j][k4 * 4];
                acc[j] += x.x * w0 + x.y * w1 + x.z * w2 + x.w * w3;
            }
        }
        __syncthreads();   // previous stage-2 readers of Hs are done
#pragma unroll
        for (int j = 0; j < 8; ++j) Hs[rg * 8 + j][col] = gelu(acc[j]);
        __syncthreads();
        const float* Wo = tWout + (size_t)i * DT * DT;
        float out[8];
        float bo = tbout[i * DT + col];
#pragma unroll
        for (int j = 0; j < 8; ++j) out[j] = bo;
        for (int k4 = 0; k4 < DT / 4; ++k4) {
            float w0 = Wo[(k4 * 4 + 0) * DT + col];
            float w1 = Wo[(k4 * 4 + 1) * DT + col];
            float w2 = Wo[(k4 * 4 + 2) * DT + col];
            float w3 = Wo[(k4 * 4 + 3) * DT + col];
#pragma unroll
            for (int j = 0; j < 8; ++j) {
                float4 x = *(const float4*)&Hs[rg * 8 + j][k4 * 4];
                out[j] += x.x * w0 + x.y * w1 + x.z * w2 + x.w * w3;
            }
        }
#pragma unroll
        for (int j = 0; j < 8; ++j) {
            int r = rg * 8 + j;
            if (r < nrows) tab[((size_t)i * N + n0 + r) * DT + col] = out[j];
        }
    }
}

// ---------------------------------------------------------------------------
// per-edge: path gather-mean -> small MLP -> + dist_tab lookup -> base_attn[E][H]
// ---------------------------------------------------------------------------
__global__ __launch_bounds__(256) void k_edge_pre(
    const int* __restrict__ path, const int* __restrict__ vp, const int* __restrict__ sl,
    const float* __restrict__ tab, const float* __restrict__ dist_tab,
    const float* __restrict__ pW1, const float* __restrict__ pb1,
    const float* __restrict__ pW2, const float* __restrict__ pb2,
    float* __restrict__ base_attn, int E, int N)
{
    __shared__ float W1t[DT][DT];   // transposed: W1t[c][k] = pW1[k][c]
    __shared__ float W2s[DT][H];
    __shared__ float b1s[DT];
    __shared__ float b2s[H];
    __shared__ float dts[8][H];
    int t = threadIdx.x;
    for (int i = t; i < DT * DT; i += 256) {
        int k = i >> 5, c = i & 31;
        W1t[c][k] = pW1[i];
    }
    if (t < DT * H) W2s[t >> 2][t & 3] = pW2[t];
    if (t < DT) b1s[t] = pb1[t];
    if (t < H)  b2s[t] = pb2[t];
    if (t < 32) dts[t >> 2][t & 3] = dist_tab[t];
    __syncthreads();
    int e = blockIdx.x * 256 + t;
    if (e >= E) return;
    int pl = 0;
    float acc[DT];
#pragma unroll
    for (int c = 0; c < DT; ++c) acc[c] = 0.0f;
#pragma unroll
    for (int i = 0; i < PP; ++i) {
        int p = path[(size_t)e * PP + i];
        if (p < -99) p = -1;
        if (p >= 0) {
            ++pl;
            const float* row = tab + ((size_t)i * N + p) * DT;
#pragma unroll
            for (int c4 = 0; c4 < 8; ++c4) {
                float4 v = *(const float4*)(row + c4 * 4);
                acc[c4 * 4 + 0] += v.x; acc[c4 * 4 + 1] += v.y;
                acc[c4 * 4 + 2] += v.z; acc[c4 * 4 + 3] += v.w;
            }
        }
    }
    float inv = 1.0f / (float)(pl > 0 ? pl : 1);
#pragma unroll
    for (int c = 0; c < DT; ++c) acc[c] *= inv;
    float o0 = b2s[0], o1 = b2s[1], o2 = b2s[2], o3 = b2s[3];
    for (int c = 0; c < DT; ++c) {
        float s = b1s[c];
#pragma unroll
        for (int k4 = 0; k4 < 8; ++k4) {
            float4 w = *(const float4*)&W1t[c][k4 * 4];
            s += acc[k4 * 4 + 0] * w.x + acc[k4 * 4 + 1] * w.y +
                 acc[k4 * 4 + 2] * w.z + acc[k4 * 4 + 3] * w.w;
        }
        float hv = gelu(s);
        o0 += hv * W2s[c][0]; o1 += hv * W2s[c][1];
        o2 += hv * W2s[c][2]; o3 += hv * W2s[c][3];
    }
    int se = (sl[e] == 1) ? 7 : ((vp[e] == 1) ? 6 : pl);
    float4 ov = make_float4(o0 + dts[se][0], o1 + dts[se][1],
                            o2 + dts[se][2], o3 + dts[se][3]);
    *(float4*)(base_attn + (size_t)e * 4) = ov;
}

// ---------------------------------------------------------------------------
// CSR build over dst
// ---------------------------------------------------------------------------
__global__ void k_count(const int* __restrict__ dst, int* __restrict__ deg, int E) {
    int e = blockIdx.x * 256 + threadIdx.x;
    if (e < E) atomicAdd(&deg[dst[e]], 1);
}

__global__ __launch_bounds__(1024) void k_scan(const int* __restrict__ deg,
                                               int* __restrict__ rowstart, int N) {
    __shared__ int sdata[1024];
    __shared__ int soff;
    int t = threadIdx.x;
    if (t == 0) soff = 0;
    for (int base = 0; base < N; base += 1024) {
        int v = (base + t < N) ? deg[base + t] : 0;
        __syncthreads();
        sdata[t] = v;
        __syncthreads();
        for (int off = 1; off < 1024; off <<= 1) {
            int x = (t >= off) ? sdata[t - off] : 0;
            __syncthreads();
            sdata[t] += x;
            __syncthreads();
        }
        int incl  = sdata[t];
        int total = sdata[1023];
        if (base + t < N) rowstart[base + t] = soff + incl - v;
        __syncthreads();
        if (t == 0) soff += total;
    }
    __syncthreads();
    if (t == 0) rowstart[N] = soff;
}

__global__ void k_scatter(const int* __restrict__ dst, const int* __restrict__ rowstart,
                          int* __restrict__ cursor, int* __restrict__ el, int E) {
    int e = blockIdx.x * 256 + threadIdx.x;
    if (e >= E) return;
    int d = dst[e];
    int pos = atomicAdd(&cursor[d], 1);
    el[rowstart[d] + pos] = e;
}

// ---------------------------------------------------------------------------
// LayerNorm: one wave per row of 128
// ---------------------------------------------------------------------------
__global__ __launch_bounds__(256) void k_ln(const float* __restrict__ X, const float* __restrict__ g,
                                            const float* __restrict__ b, float* __restrict__ out, int N) {
    int gw   = (blockIdx.x * 256 + threadIdx.x) >> 6;
    int lane = threadIdx.x & 63;
    if (gw >= N) return;
    const float* x = X + (size_t)gw * D;
    float a0 = x[lane], a1 = x[lane + 64];
    float s = a0 + a1;
#pragma unroll
    for (int m = 1; m < 64; m <<= 1) s += __shfl_xor(s, m);
    float mu = s * (1.0f / 128.0f);
    float d0 = a0 - mu, d1 = a1 - mu;
    float v = d0 * d0 + d1 * d1;
#pragma unroll
    for (int m = 1; m < 64; m <<= 1) v += __shfl_xor(v, m);
    float r = rsqrtf(v * (1.0f / 128.0f) + 1e-5f);
    float* o = out + (size_t)gw * D;
    o[lane]      = d0 * r * g[lane]      + b[lane];
    o[lane + 64] = d1 * r * g[lane + 64] + b[lane + 64];
}

// ---------------------------------------------------------------------------
// qkv GEMM: (N x 128) @ (128 x 384) + bias. block: 32 rows, 256 threads
// thread: 4 rows x 12 contiguous cols
// ---------------------------------------------------------------------------
__global__ __launch_bounds__(256) void k_qkv(const float* __restrict__ A, const float* __restrict__ W,
                                             const float* __restrict__ bias, float* __restrict__ C, int N) {
    __shared__ float As[32][D];
    int t = threadIdx.x;
    int n0 = blockIdx.x * 32;
    int nrows = N - n0; if (nrows > 32) nrows = 32;
    for (int i = t; i < 32 * D; i += 256) {
        int r = i >> 7, c = i & 127;
        As[r][c] = (r < nrows) ? A[(size_t)(n0 + r) * D + c] : 0.0f;
    }
    __syncthreads();
    int rg = t >> 5;
    int r0 = rg * 4;
    int c0 = (t & 31) * 12;
    float acc[4][12];
#pragma unroll
    for (int r = 0; r < 4; ++r)
#pragma unroll
        for (int j = 0; j < 12; ++j) acc[r][j] = 0.0f;
    for (int k4 = 0; k4 < D / 4; ++k4) {
        float av[4][4];
#pragma unroll
        for (int r = 0; r < 4; ++r) {
            float4 x = *(const float4*)&As[r0 + r][k4 * 4];
            av[r][0] = x.x; av[r][1] = x.y; av[r][2] = x.z; av[r][3] = x.w;
        }
#pragma unroll
        for (int u = 0; u < 4; ++u) {
            const float* wr = W + (size_t)(k4 * 4 + u) * 384 + c0;
            float4 w0 = *(const float4*)(wr);
            float4 w1 = *(const float4*)(wr + 4);
            float4 w2 = *(const float4*)(wr + 8);
            float wv[12] = { w0.x, w0.y, w0.z, w0.w, w1.x, w1.y, w1.z, w1.w,
                             w2.x, w2.y, w2.z, w2.w };
#pragma unroll
            for (int r = 0; r < 4; ++r)
#pragma unroll
                for (int j = 0; j < 12; ++j) acc[r][j] += av[r][u] * wv[j];
        }
    }
    float bv[12];
#pragma unroll
    for (int j = 0; j < 12; ++j) bv[j] = bias[c0 + j];
#pragma unroll
    for (int r = 0; r < 4; ++r) {
        if (r0 + r < nrows) {
            float* out = C + (size_t)(n0 + r0 + r) * 384 + c0;
#pragma unroll
            for (int j = 0; j < 12; ++j) out[j] = acc[r][j] + bv[j];
        }
    }
}

// ---------------------------------------------------------------------------
// per-edge attention logits -> exp  (wave per edge)
// ---------------------------------------------------------------------------
__global__ __launch_bounds__(256) void k_edge_attn(const float* __restrict__ qkv,
        const int* __restrict__ src, const int* __restrict__ dst,
        const float* __restrict__ base_attn, float* __restrict__ ex, int E) {
    int gw   = (blockIdx.x * 256 + threadIdx.x) >> 6;
    int lane = threadIdx.x & 63;
    if (gw >= E) return;
    int s = src[gw], d = dst[gw];
    const float* qs = qkv + (size_t)s * 384;
    const float* kd = qkv + (size_t)d * 384 + 128;
    float q0 = qs[lane] * SCALE, q1 = qs[lane + 64] * SCALE;
    float k0 = kd[lane],         k1 = kd[lane + 64];
    float t0 = q0 * k0, t1 = q1 * k1;
#pragma unroll
    for (int m = 1; m <= 16; m <<= 1) { t0 += __shfl_xor(t0, m); t1 += __shfl_xor(t1, m); }
    // heads: t0 -> head0 (lanes 0..31) / head1 (lanes 32..63); t1 -> head2/head3
    if (lane == 0) {
        ex[(size_t)gw * 4 + 0] = expf(t0 + base_attn[(size_t)gw * 4 + 0]);
        ex[(size_t)gw * 4 + 2] = expf(t1 + base_attn[(size_t)gw * 4 + 2]);
    } else if (lane == 32) {
        ex[(size_t)gw * 4 + 1] = expf(t0 + base_attn[(size_t)gw * 4 + 1]);
        ex[(size_t)gw * 4 + 3] = expf(t1 + base_attn[(size_t)gw * 4 + 3]);
    }
}

// ---------------------------------------------------------------------------
// softmax-normalize + aggregate v  (wave per node, CSR over dst)
// ---------------------------------------------------------------------------
__global__ __launch_bounds__(256) void k_agg(const float* __restrict__ qkv,
        const int* __restrict__ rowstart, const int* __restrict__ el,
        const int* __restrict__ src, const float* __restrict__ ex,
        float* __restrict__ agg, int N) {
    int gw   = (blockIdx.x * 256 + threadIdx.x) >> 6;
    int lane = threadIdx.x & 63;
    if (gw >= N) return;
    int beg = rowstart[gw], end = rowstart[gw + 1];
    int h0 = lane >> 5;        // head of element d=lane (0/1); d+64 -> h0+2
    float s0 = 0.0f, s1 = 0.0f;
    for (int i = beg; i < end; ++i) {
        int e = el[i];
        s0 += ex[(size_t)e * 4 + h0];
        s1 += ex[(size_t)e * 4 + h0 + 2];
    }
    float inv0 = (s0 > 0.0f) ? 1.0f / s0 : 0.0f;
    float inv1 = (s1 > 0.0f) ? 1.0f / s1 : 0.0f;
    float a0 = 0.0f, a1 = 0.0f;
    for (int i = beg; i < end; ++i) {
        int e  = el[i];
        int sr = src[e];
        const float* v = qkv + (size_t)sr * 384 + 256;
        float w0 = ex[(size_t)e * 4 + h0]     * inv0;
        float w1 = ex[(size_t)e * 4 + h0 + 2] * inv1;
        a0 += w0 * v[lane];
        a1 += w1 * v[lane + 64];
    }
    agg[(size_t)gw * D + lane]      = a0;
    agg[(size_t)gw * D + lane + 64] = a1;
}

// ---------------------------------------------------------------------------
// res GEMM: x = resid + agg @ res_W + res_b. block: 64 rows, 256 threads
// ---------------------------------------------------------------------------
__global__ __launch_bounds__(256) void k_res(const float* __restrict__ A, const float* __restrict__ W,
        const float* __restrict__ bias, const float* __restrict__ resid,
        float* __restrict__ Out, int N) {
    __shared__ float As[64][D];
    int t = threadIdx.x;
    int n0 = blockIdx.x * 64;
    int nrows = N - n0; if (nrows > 64) nrows = 64;
    for (int i = t; i < 64 * D; i += 256) {
        int r = i >> 7, c = i & 127;
        As[r][c] = (r < nrows) ? A[(size_t)(n0 + r) * D + c] : 0.0f;
    }
    __syncthreads();
    int rg = t >> 5;
    int c0 = (t & 31) * 4;
    float acc[8][4];
#pragma unroll
    for (int rr = 0; rr < 8; ++rr)
#pragma unroll
        for (int j = 0; j < 4; ++j) acc[rr][j] = 0.0f;
    for (int k4 = 0; k4 < D / 4; ++k4) {
        float av[8][4];
#pragma unroll
        for (int rr = 0; rr < 8; ++rr) {
            float4 x = *(const float4*)&As[rg * 8 + rr][k4 * 4];
            av[rr][0] = x.x; av[rr][1] = x.y; av[rr][2] = x.z; av[rr][3] = x.w;
        }
#pragma unroll
        for (int u = 0; u < 4; ++u) {
            float4 w = *(const float4*)(W + (size_t)(k4 * 4 + u) * D + c0);
#pragma unroll
            for (int rr = 0; rr < 8; ++rr) {
                acc[rr][0] += av[rr][u] * w.x; acc[rr][1] += av[rr][u] * w.y;
                acc[rr][2] += av[rr][u] * w.z; acc[rr][3] += av[rr][u] * w.w;
            }
        }
    }
    float4 bv = *(const float4*)(bias + c0);
#pragma unroll
    for (int rr = 0; rr < 8; ++rr) {
        int r = rg * 8 + rr;
        if (r < nrows) {
            size_t o = (size_t)(n0 + r) * D + c0;
            float4 rv = *(const float4*)(resid + o);
            float4 ov;
            ov.x = acc[rr][0] + bv.x + rv.x;
            ov.y = acc[rr][1] + bv.y + rv.y;
            ov.z = acc[rr][2] + bv.z + rv.z;
            ov.w = acc[rr][3] + bv.w + rv.w;
            *(float4*)(Out + o) = ov;
        }
    }
}

// ---------------------------------------------------------------------------
// fused FFN: Out = Xres + gelu(Hin@Win+bin)@Wout+bout. block: 16 rows
// ---------------------------------------------------------------------------
__global__ __launch_bounds__(256) void k_ffn(const float* __restrict__ Hin, const float* __restrict__ Xres,
        const float* __restrict__ Win, const float* __restrict__ bin,
        const float* __restrict__ Wout, const float* __restrict__ bout,
        float* __restrict__ Out, int N)
{
    __shared__ float hs[16][D];
    __shared__ float hid[16][FF];
    int t = threadIdx.x;
    int n0 = blockIdx.x * 16;
    int nrows = N - n0; if (nrows > 16) nrows = 16;
    for (int i = t; i < nrows * D; i += 256) {
        int r = i >> 7, c = i & 127;
        hs[r][c] = Hin[(size_t)(n0 + r) * D + c];
    }
    __syncthreads();
    {
        int f0 = t, f1 = t + 256;
        float a0[16], a1[16];
        float bb0 = bin[f0], bb1 = bin[f1];
#pragma unroll
        for (int r = 0; r < 16; ++r) { a0[r] = bb0; a1[r] = bb1; }
        for (int k4 = 0; k4 < D / 4; ++k4) {
            float w0[4], w1[4];
#pragma unroll
            for (int u = 0; u < 4; ++u) {
                w0[u] = Win[(size_t)(k4 * 4 + u) * FF + f0];
                w1[u] = Win[(size_t)(k4 * 4 + u) * FF + f1];
            }
#pragma unroll
            for (int r = 0; r < 16; ++r) {
                float4 x = *(const float4*)&hs[r][k4 * 4];
                a0[r] += x.x * w0[0] + x.y * w0[1] + x.z * w0[2] + x.w * w0[3];
                a1[r] += x.x * w1[0] + x.y * w1[1] + x.z * w1[2] + x.w * w1[3];
            }
        }
#pragma unroll
        for (int r = 0; r < 16; ++r) { hid[r][f0] = gelu(a0[r]); hid[r][f1] = gelu(a1[r]); }
    }
    __syncthreads();
    {
        int dd = t & 127;
        int rh = t >> 7;
        float o[8];
        float bb = bout[dd];
#pragma unroll
        for (int j = 0; j < 8; ++j) o[j] = bb;
        for (int k4 = 0; k4 < FF / 4; ++k4) {
            float w[4];
#pragma unroll
            for (int u = 0; u < 4; ++u) w[u] = Wout[(size_t)(k4 * 4 + u) * D + dd];
#pragma unroll
            for (int j = 0; j < 8; ++j) {
                float4 x = *(const float4*)&hid[rh * 8 + j][k4 * 4];
                o[j] += x.x * w[0] + x.y * w[1] + x.z * w[2] + x.w * w[3];
            }
        }
#pragma unroll
        for (int j = 0; j < 8; ++j) {
            int r = rh * 8 + j;
            if (r < nrows) {
                size_t ofs = (size_t)(n0 + r) * D + dd;
                Out[ofs] = Xres[ofs] + o[j];
            }
        }
    }
}

// ---------------------------------------------------------------------------
extern "C" void kernel_launch(void* const* d_in, const int* in_sizes, int n_in,
                              void* d_out, int out_size, void* d_ws, size_t ws_size,
                              hipStream_t stream) {
    const float* triplet_h = (const float*)d_in[0];
    const float* ple    = (const float*)d_in[1];
    const float* vpe    = (const float*)d_in[2];
    const float* sle    = (const float*)d_in[3];
    const float* dW1    = (const float*)d_in[4];
    const float* db1    = (const float*)d_in[5];
    const float* dW2    = (const float*)d_in[6];
    const float* db2    = (const float*)d_in[7];
    const float* tWin   = (const float*)d_in[8];
    const float* tbin   = (const float*)d_in[9];
    const float* tWout  = (const float*)d_in[10];
    const float* tbout  = (const float*)d_in[11];
    const float* pW1    = (const float*)d_in[12];
    const float* pb1    = (const float*)d_in[13];
    const float* pW2    = (const float*)d_in[14];
    const float* pb2    = (const float*)d_in[15];
    const float* ln1_g  = (const float*)d_in[16];
    const float* ln1_b  = (const float*)d_in[17];
    const float* qkv_W  = (const float*)d_in[18];
    const float* qkv_b  = (const float*)d_in[19];
    const float* rln_g  = (const float*)d_in[20];
    const float* rln_b  = (const float*)d_in[21];
    const float* res_W  = (const float*)d_in[22];
    const float* res_b  = (const float*)d_in[23];
    const float* fWin   = (const float*)d_in[24];
    const float* fbin   = (const float*)d_in[25];
    const float* fWout  = (const float*)d_in[26];
    const float* fbout  = (const float*)d_in[27];
    const int*   srcp   = (const int*)d_in[28];
    const int*   dstp   = (const int*)d_in[29];
    const int*   path   = (const int*)d_in[30];
    const int*   vp     = (const int*)d_in[31];
    const int*   sl     = (const int*)d_in[32];

    const int N = in_sizes[0] / D;
    const int E = in_sizes[28];

    char* ws = (char*)d_ws;
    size_t off = 0;
    auto alloc = [&](size_t bytes) -> void* {
        void* p = ws + off;
        off += (bytes + 255) & ~(size_t)255;
        return p;
    };
    float* tab      = (float*)alloc((size_t)PP * N * DT * 4);
    float* dist_tab = (float*)alloc(8 * H * 4);
    float* base_attn= (float*)alloc((size_t)E * H * 4);
    int*   deg      = (int*)alloc((size_t)N * 4);
    int*   rowstart = (int*)alloc((size_t)(N + 1) * 4);
    int*   cursor   = (int*)alloc((size_t)N * 4);
    int*   el       = (int*)alloc((size_t)E * 4);
    float* hbuf     = (float*)alloc((size_t)N * D * 4);
    float* qkvbuf   = (float*)alloc((size_t)N * 384 * 4);
    float* exbuf    = (float*)alloc((size_t)E * H * 4);
    float* aggbuf   = (float*)alloc((size_t)N * D * 4);
    float* bufA     = (float*)alloc((size_t)N * D * 4);
    float* bufB     = (float*)alloc((size_t)N * D * 4);
    if (off > ws_size) return;   // workspace too small -> fail loudly (poisoned output)

    hipMemsetAsync(deg,    0, (size_t)N * 4, stream);
    hipMemsetAsync(cursor, 0, (size_t)N * 4, stream);

    k_dist_tab<<<1, 256, 0, stream>>>(ple, vpe, sle, dW1, db1, dW2, db2, dist_tab);
    k_tab<<<(N + 63) / 64, 256, 0, stream>>>(triplet_h, tWin, tbin, tWout, tbout, tab, N);
    k_edge_pre<<<(E + 255) / 256, 256, 0, stream>>>(path, vp, sl, tab, dist_tab,
                                                    pW1, pb1, pW2, pb2, base_attn, E, N);
    k_count<<<(E + 255) / 256, 256, 0, stream>>>(dstp, deg, E);
    k_scan<<<1, 1024, 0, stream>>>(deg, rowstart, N);
    k_scatter<<<(E + 255) / 256, 256, 0, stream>>>(dstp, rowstart, cursor, el, E);

    hipMemcpyAsync(bufA, triplet_h, (size_t)N * D * 4, hipMemcpyDeviceToDevice, stream);

    for (int l = 0; l < NL; ++l) {
        k_ln<<<(N + 3) / 4, 256, 0, stream>>>(bufA, ln1_g + l * D, ln1_b + l * D, hbuf, N);
        k_qkv<<<(N + 31) / 32, 256, 0, stream>>>(hbuf, qkv_W + (size_t)l * D * 384,
                                                 qkv_b + l * 384, qkvbuf, N);
        k_edge_attn<<<(E + 3) / 4, 256, 0, stream>>>(qkvbuf, srcp, dstp, base_attn, exbuf, E);
        k_agg<<<(N + 3) / 4, 256, 0, stream>>>(qkvbuf, rowstart, el, srcp, exbuf, aggbuf, N);
        k_res<<<(N + 63) / 64, 256, 0, stream>>>(aggbuf, res_W + (size_t)l * D * D,
                                                 res_b + l * D, bufA, bufB, N);
        k_ln<<<(N + 3) / 4, 256, 0, stream>>>(bufB, rln_g + l * D, rln_b + l * D, hbuf, N);
        k_ffn<<<(N + 15) / 16, 256, 0, stream>>>(hbuf, bufB, fWin + (size_t)l * D * FF,
                                                 fbin + l * FF, fWout + (size_t)l * FF * D,
                                                 fbout + l * D, bufA, N);
    }

    hipMemcpyAsync(d_out, bufA, (size_t)N * D * 4, hipMemcpyDeviceToDevice, stream);
}

// Round 5
// 1258.382 us; speedup vs baseline: 1.2678x; 1.2678x over previous
//
#include <hip/hip_runtime.h>
#include <math.h>

#define D   128
#define H   4
#define PP  5
#define DT  32
#define FF  512
#define NL  2
#define SCALE 0.08838834764831845f

typedef _Float16 f16x8 __attribute__((ext_vector_type(8)));
typedef float    f32x4 __attribute__((ext_vector_type(4)));

__device__ __forceinline__ float gelu(float x) {
    return 0.5f * x * (1.0f + erff(x * 0.7071067811865476f));
}

__device__ __forceinline__ f16x8 f16x8_zero() {
    f16x8 v;
#pragma unroll
    for (int j = 0; j < 8; ++j) v[j] = (_Float16)0.0f;
    return v;
}

// ---------------------------------------------------------------------------
// weight prep: transpose-convert f32 W[K][C] -> f16 Wt[C][K]
// ---------------------------------------------------------------------------
struct WPrep {
    const float* src[8];
    _Float16*    dst[8];
    int K[8], C[8];
};

__global__ __launch_bounds__(256) void k_wprep(WPrep p) {
    int m = blockIdx.y;
    int n = blockIdx.x * 256 + threadIdx.x;
    int K = p.K[m], C = p.C[m];
    if (n >= K * C) return;
    int c = n / K, k = n - c * K;
    p.dst[m][n] = (_Float16)p.src[m][(size_t)k * C + c];
}

// ---------------------------------------------------------------------------
// dist_attn table: 8 possible pf vectors -> gelu(pf@dW1+db1)@dW2+db2  (8 x H)
// ---------------------------------------------------------------------------
__global__ __launch_bounds__(256) void k_dist_tab(
    const float* __restrict__ ple, const float* __restrict__ vpe, const float* __restrict__ sle,
    const float* __restrict__ dW1, const float* __restrict__ db1,
    const float* __restrict__ dW2, const float* __restrict__ db2,
    float* __restrict__ dist_tab)
{
    __shared__ float pf[8][D];
    __shared__ float hid[8][D];
    int t = threadIdx.x;
    for (int i = t; i < 8 * D; i += 256) {
        int r = i >> 7, c = i & 127;
        float v;
        if (r < 6)      v = ple[r * D + c];
        else if (r == 6) v = vpe[c];
        else             v = sle[c];
        pf[r][c] = v;
    }
    __syncthreads();
    for (int i = t; i < 8 * D; i += 256) {
        int r = i >> 7, c = i & 127;
        float s = db1[c];
        for (int k = 0; k < D; ++k) s += pf[r][k] * dW1[k * D + c];
        hid[r][c] = gelu(s);
    }
    __syncthreads();
    if (t < 8 * H) {
        int r = t >> 2, h = t & 3;
        float s = db2[h];
        for (int k = 0; k < D; ++k) s += hid[r][k] * dW2[k * H + h];
        dist_tab[r * H + h] = s;
    }
}

// ---------------------------------------------------------------------------
// tab[i][n][:] = gelu(X[n]@tWin[i]+tbin[i]) @ tWout[i] + tbout[i]
// ---------------------------------------------------------------------------
__global__ __launch_bounds__(256) void k_tab(
    const float* __restrict__ X, const float* __restrict__ tWin, const float* __restrict__ tbin,
    const float* __restrict__ tWout, const float* __restrict__ tbout,
    float* __restrict__ tab, int N)
{
    __shared__ float Xs[64][D];
    __shared__ float Hs[64][DT];
    int t = threadIdx.x;
    int n0 = blockIdx.x * 64;
    int nrows = N - n0; if (nrows > 64) nrows = 64;
    for (int i = t; i < 64 * D; i += 256) {
        int r = i >> 7, c = i & 127;
        Xs[r][c] = (r < nrows) ? X[(size_t)(n0 + r) * D + c] : 0.0f;
    }
    int col = t & 31;
    int rg  = t >> 5;
    __syncthreads();
    for (int i = 0; i < PP; ++i) {
        const float* Wi = tWin + (size_t)i * D * DT;
        float acc[8];
        float b = tbin[i * DT + col];
#pragma unroll
        for (int j = 0; j < 8; ++j) acc[j] = b;
        for (int k4 = 0; k4 < D / 4; ++k4) {
            float w0 = Wi[(k4 * 4 + 0) * DT + col];
            float w1 = Wi[(k4 * 4 + 1) * DT + col];
            float w2 = Wi[(k4 * 4 + 2) * DT + col];
            float w3 = Wi[(k4 * 4 + 3) * DT + col];
#pragma unroll
            for (int j = 0; j < 8; ++j) {
                float4 x = *(const float4*)&Xs[rg * 8 + j][k4 * 4];
                acc[j] += x.x * w0 + x.y * w1 + x.z * w2 + x.w * w3;
            }
        }
        __syncthreads();
#pragma unroll
        for (int j = 0; j < 8; ++j) Hs[rg * 8 + j][col] = gelu(acc[j]);
        __syncthreads();
        const float* Wo = tWout + (size_t)i * DT * DT;
        float out[8];
        float bo = tbout[i * DT + col];
#pragma unroll
        for (int j = 0; j < 8; ++j) out[j] = bo;
        for (int k4 = 0; k4 < DT / 4; ++k4) {
            float w0 = Wo[(k4 * 4 + 0) * DT + col];
            float w1 = Wo[(k4 * 4 + 1) * DT + col];
            float w2 = Wo[(k4 * 4 + 2) * DT + col];
            float w3 = Wo[(k4 * 4 + 3) * DT + col];
#pragma unroll
            for (int j = 0; j < 8; ++j) {
                float4 x = *(const float4*)&Hs[rg * 8 + j][k4 * 4];
                out[j] += x.x * w0 + x.y * w1 + x.z * w2 + x.w * w3;
            }
        }
#pragma unroll
        for (int j = 0; j < 8; ++j) {
            int r = rg * 8 + j;
            if (r < nrows) tab[((size_t)i * N + n0 + r) * DT + col] = out[j];
        }
    }
}

// ---------------------------------------------------------------------------
// per-edge: path gather-mean -> small MLP -> + dist_tab lookup
// ---------------------------------------------------------------------------
__global__ __launch_bounds__(256) void k_edge_pre(
    const int* __restrict__ path, const int* __restrict__ vp, const int* __restrict__ sl,
    const float* __restrict__ tab, const float* __restrict__ dist_tab,
    const float* __restrict__ pW1, const float* __restrict__ pb1,
    const float* __restrict__ pW2, const float* __restrict__ pb2,
    float* __restrict__ base_attn, int E, int N)
{
    __shared__ float W1t[DT][DT];
    __shared__ float W2s[DT][H];
    __shared__ float b1s[DT];
    __shared__ float b2s[H];
    __shared__ float dts[8][H];
    int t = threadIdx.x;
    for (int i = t; i < DT * DT; i += 256) {
        int k = i >> 5, c = i & 31;
        W1t[c][k] = pW1[i];
    }
    if (t < DT * H) W2s[t >> 2][t & 3] = pW2[t];
    if (t < DT) b1s[t] = pb1[t];
    if (t < H)  b2s[t] = pb2[t];
    if (t < 32) dts[t >> 2][t & 3] = dist_tab[t];
    __syncthreads();
    int e = blockIdx.x * 256 + t;
    if (e >= E) return;
    int pl = 0;
    float acc[DT];
#pragma unroll
    for (int c = 0; c < DT; ++c) acc[c] = 0.0f;
#pragma unroll
    for (int i = 0; i < PP; ++i) {
        int p = path[(size_t)e * PP + i];
        if (p < -99) p = -1;
        if (p >= 0) {
            ++pl;
            const float* row = tab + ((size_t)i * N + p) * DT;
#pragma unroll
            for (int c4 = 0; c4 < 8; ++c4) {
                float4 v = *(const float4*)(row + c4 * 4);
                acc[c4 * 4 + 0] += v.x; acc[c4 * 4 + 1] += v.y;
                acc[c4 * 4 + 2] += v.z; acc[c4 * 4 + 3] += v.w;
            }
        }
    }
    float inv = 1.0f / (float)(pl > 0 ? pl : 1);
#pragma unroll
    for (int c = 0; c < DT; ++c) acc[c] *= inv;
    float o0 = b2s[0], o1 = b2s[1], o2 = b2s[2], o3 = b2s[3];
    for (int c = 0; c < DT; ++c) {
        float s = b1s[c];
#pragma unroll
        for (int k4 = 0; k4 < 8; ++k4) {
            float4 w = *(const float4*)&W1t[c][k4 * 4];
            s += acc[k4 * 4 + 0] * w.x + acc[k4 * 4 + 1] * w.y +
                 acc[k4 * 4 + 2] * w.z + acc[k4 * 4 + 3] * w.w;
        }
        float hv = gelu(s);
        o0 += hv * W2s[c][0]; o1 += hv * W2s[c][1];
        o2 += hv * W2s[c][2]; o3 += hv * W2s[c][3];
    }
    int se = (sl[e] == 1) ? 7 : ((vp[e] == 1) ? 6 : pl);
    float4 ov = make_float4(o0 + dts[se][0], o1 + dts[se][1],
                            o2 + dts[se][2], o3 + dts[se][3]);
    *(float4*)(base_attn + (size_t)e * 4) = ov;
}

// ---------------------------------------------------------------------------
// CSR build over dst
// ---------------------------------------------------------------------------
__global__ void k_count(const int* __restrict__ dst, int* __restrict__ deg, int E) {
    int e = blockIdx.x * 256 + threadIdx.x;
    if (e < E) atomicAdd(&deg[dst[e]], 1);
}

__global__ __launch_bounds__(1024) void k_scan(const int* __restrict__ deg,
                                               int* __restrict__ rowstart, int N) {
    __shared__ int sdata[1024];
    __shared__ int soff;
    int t = threadIdx.x;
    if (t == 0) soff = 0;
    for (int base = 0; base < N; base += 1024) {
        int v = (base + t < N) ? deg[base + t] : 0;
        __syncthreads();
        sdata[t] = v;
        __syncthreads();
        for (int off = 1; off < 1024; off <<= 1) {
            int x = (t >= off) ? sdata[t - off] : 0;
            __syncthreads();
            sdata[t] += x;
            __syncthreads();
        }
        int incl  = sdata[t];
        int total = sdata[1023];
        if (base + t < N) rowstart[base + t] = soff + incl - v;
        __syncthreads();
        if (t == 0) soff += total;
    }
    __syncthreads();
    if (t == 0) rowstart[N] = soff;
}

__global__ void k_scatter(const int* __restrict__ dst, const int* __restrict__ rowstart,
                          int* __restrict__ cursor, int* __restrict__ el, int E) {
    int e = blockIdx.x * 256 + threadIdx.x;
    if (e >= E) return;
    int d = dst[e];
    int pos = atomicAdd(&cursor[d], 1);
    el[rowstart[d] + pos] = e;
}

// ---------------------------------------------------------------------------
// LayerNorm: one wave per row of 128, writes f16 for MFMA consumers
// ---------------------------------------------------------------------------
__global__ __launch_bounds__(256) void k_ln(const float* __restrict__ X, const float* __restrict__ g,
                                            const float* __restrict__ b, _Float16* __restrict__ out, int N) {
    int gw   = (blockIdx.x * 256 + threadIdx.x) >> 6;
    int lane = threadIdx.x & 63;
    if (gw >= N) return;
    const float* x = X + (size_t)gw * D;
    float a0 = x[lane], a1 = x[lane + 64];
    float s = a0 + a1;
#pragma unroll
    for (int m = 1; m < 64; m <<= 1) s += __shfl_xor(s, m);
    float mu = s * (1.0f / 128.0f);
    float d0 = a0 - mu, d1 = a1 - mu;
    float v = d0 * d0 + d1 * d1;
#pragma unroll
    for (int m = 1; m < 64; m <<= 1) v += __shfl_xor(v, m);
    float r = rsqrtf(v * (1.0f / 128.0f) + 1e-5f);
    _Float16* o = out + (size_t)gw * D;
    o[lane]      = (_Float16)(d0 * r * g[lane]      + b[lane]);
    o[lane + 64] = (_Float16)(d1 * r * g[lane + 64] + b[lane + 64]);
}

// ---------------------------------------------------------------------------
// MFMA fragment conventions (gfx950 16x16x32, HW-verified layout):
//   A-frag: lane l holds A[m=l&15][k=(l>>4)*8 + 0..7]   (contig 16B)
//   B-frag: lane l holds B[k=(l>>4)*8+j][n=l&15] -> from Wt[n][k] contig 16B
//   C/D   : col = l&15, row = (l>>4)*4 + reg
// ---------------------------------------------------------------------------

// qkv GEMM: C[N][384] = A[N][128] @ W[128][384] + bias. block 64 rows, 4 waves
__global__ __launch_bounds__(256) void k_qkv_mfma(
    const _Float16* __restrict__ Hin, const _Float16* __restrict__ Wt, // [384][128]
    const float* __restrict__ bias, float* __restrict__ C, int N)
{
    __shared__ _Float16 Ah[64][136];   // pad 8 f16: row stride 272B -> conflict-free frags
    int t = threadIdx.x;
    int n0 = blockIdx.x * 64;
#pragma unroll
    for (int i = 0; i < 4; ++i) {
        int flat = t + i * 256;
        int r = flat >> 4, c = flat & 15;
        f16x8 v = f16x8_zero();
        if (n0 + r < N) v = *(const f16x8*)&Hin[(size_t)(n0 + r) * D + c * 8];
        *(f16x8*)&Ah[r][c * 8] = v;
    }
    __syncthreads();
    int w = t >> 6, lane = t & 63;
    int rt0 = w * 16, lr = lane & 15, lg = lane >> 4;
    f16x8 a1[4];
#pragma unroll
    for (int kk = 0; kk < 4; ++kk)
        a1[kk] = *(const f16x8*)&Ah[rt0 + lr][kk * 32 + lg * 8];
#pragma unroll 4
    for (int ct = 0; ct < 24; ++ct) {
        int col = ct * 16 + lr;
        f32x4 acc = {0.f, 0.f, 0.f, 0.f};
#pragma unroll
        for (int kk = 0; kk < 4; ++kk) {
            f16x8 b = *(const f16x8*)&Wt[(size_t)col * 128 + kk * 32 + lg * 8];
            acc = __builtin_amdgcn_mfma_f32_16x16x32_f16(a1[kk], b, acc, 0, 0, 0);
        }
        float bb = bias[col];
#pragma unroll
        for (int i = 0; i < 4; ++i) {
            int row = n0 + rt0 + lg * 4 + i;
            if (row < N) C[(size_t)row * 384 + col] = acc[i] + bb;
        }
    }
}

// res GEMM: Out = resid + Agg @ res_W + bias. block 64 rows, 4 waves
__global__ __launch_bounds__(256) void k_res_mfma(
    const _Float16* __restrict__ Agg, const _Float16* __restrict__ Wt, // [128][128]
    const float* __restrict__ bias, const float* __restrict__ resid,
    float* __restrict__ Out, int N)
{
    __shared__ _Float16 Ah[64][136];
    int t = threadIdx.x;
    int n0 = blockIdx.x * 64;
#pragma unroll
    for (int i = 0; i < 4; ++i) {
        int flat = t + i * 256;
        int r = flat >> 4, c = flat & 15;
        f16x8 v = f16x8_zero();
        if (n0 + r < N) v = *(const f16x8*)&Agg[(size_t)(n0 + r) * D + c * 8];
        *(f16x8*)&Ah[r][c * 8] = v;
    }
    __syncthreads();
    int w = t >> 6, lane = t & 63;
    int rt0 = w * 16, lr = lane & 15, lg = lane >> 4;
    f16x8 a1[4];
#pragma unroll
    for (int kk = 0; kk < 4; ++kk)
        a1[kk] = *(const f16x8*)&Ah[rt0 + lr][kk * 32 + lg * 8];
#pragma unroll
    for (int ct = 0; ct < 8; ++ct) {
        int col = ct * 16 + lr;
        f32x4 acc = {0.f, 0.f, 0.f, 0.f};
#pragma unroll
        for (int kk = 0; kk < 4; ++kk) {
            f16x8 b = *(const f16x8*)&Wt[(size_t)col * 128 + kk * 32 + lg * 8];
            acc = __builtin_amdgcn_mfma_f32_16x16x32_f16(a1[kk], b, acc, 0, 0, 0);
        }
        float bb = bias[col];
#pragma unroll
        for (int i = 0; i < 4; ++i) {
            int row = n0 + rt0 + lg * 4 + i;
            if (row < N) {
                size_t o = (size_t)row * D + col;
                Out[o] = resid[o] + acc[i] + bb;
            }
        }
    }
}

// fused FFN: Out = Xres + gelu(Hin@Win+bin)@Wout+bout. block 64 rows, 4 waves
// GEMM1 -> gelu -> LDS hid (wave-private stripe) -> GEMM2, chunked K=256
__global__ __launch_bounds__(256) void k_ffn_mfma(
    const _Float16* __restrict__ Hin, const float* __restrict__ Xres,
    const _Float16* __restrict__ Wt1,  // [512][128] (Win^T)
    const float* __restrict__ bin,
    const _Float16* __restrict__ Wt2,  // [128][512] (Wout^T)
    const float* __restrict__ bout,
    float* __restrict__ Out, int N)
{
    __shared__ _Float16 Ah[64][136];
    __shared__ _Float16 hid[64][264];  // 256-col chunk + 8 pad (row stride 528B)
    int t = threadIdx.x;
    int n0 = blockIdx.x * 64;
#pragma unroll
    for (int i = 0; i < 4; ++i) {
        int flat = t + i * 256;
        int r = flat >> 4, c = flat & 15;
        f16x8 v = f16x8_zero();
        if (n0 + r < N) v = *(const f16x8*)&Hin[(size_t)(n0 + r) * D + c * 8];
        *(f16x8*)&Ah[r][c * 8] = v;
    }
    __syncthreads();
    int w = t >> 6, lane = t & 63;
    int rt0 = w * 16, lr = lane & 15, lg = lane >> 4;
    f16x8 a1[4];
#pragma unroll
    for (int kk = 0; kk < 4; ++kk)
        a1[kk] = *(const f16x8*)&Ah[rt0 + lr][kk * 32 + lg * 8];

    f32x4 acc2[8];
#pragma unroll
    for (int i = 0; i < 8; ++i) acc2[i] = (f32x4){0.f, 0.f, 0.f, 0.f};

    for (int ch = 0; ch < 2; ++ch) {
        // ---- GEMM1: hidden cols [ch*256, ch*256+256) for this wave's 16 rows
#pragma unroll 4
        for (int ct = 0; ct < 16; ++ct) {
            int hc = ch * 256 + ct * 16 + lr;   // hidden col (b-frag n / bias idx)
            f32x4 c1 = {0.f, 0.f, 0.f, 0.f};
#pragma unroll
            for (int kk = 0; kk < 4; ++kk) {
                f16x8 b = *(const f16x8*)&Wt1[(size_t)hc * 128 + kk * 32 + lg * 8];
                c1 = __builtin_amdgcn_mfma_f32_16x16x32_f16(a1[kk], b, c1, 0, 0, 0);
            }
            float bb = bin[hc];
#pragma unroll
            for (int i = 0; i < 4; ++i) {
                float v = gelu(c1[i] + bb);
                hid[rt0 + lg * 4 + i][ct * 16 + lr] = (_Float16)v;
            }
        }
        // wave-private stripe: same wave wrote rows [rt0,rt0+16) -> no barrier,
        // compiler inserts lgkmcnt waits for the LDS RAW dependence.
        // ---- GEMM2 partial: K-chunk [ch*256, ch*256+256)
#pragma unroll 2
        for (int kk2 = 0; kk2 < 8; ++kk2) {
            f16x8 a2 = *(const f16x8*)&hid[rt0 + lr][kk2 * 32 + lg * 8];
            int gk = ch * 256 + kk2 * 32 + lg * 8;
#pragma unroll
            for (int ct2 = 0; ct2 < 8; ++ct2) {
                f16x8 b2 = *(const f16x8*)&Wt2[(size_t)(ct2 * 16 + lr) * 512 + gk];
                acc2[ct2] = __builtin_amdgcn_mfma_f32_16x16x32_f16(a2, b2, acc2[ct2], 0, 0, 0);
            }
        }
    }
#pragma unroll
    for (int ct2 = 0; ct2 < 8; ++ct2) {
        int col = ct2 * 16 + lr;
        float bb = bout[col];
#pragma unroll
        for (int i = 0; i < 4; ++i) {
            int row = n0 + rt0 + lg * 4 + i;
            if (row < N) {
                size_t o = (size_t)row * D + col;
                Out[o] = Xres[o] + acc2[ct2][i] + bb;
            }
        }
    }
}

// ---------------------------------------------------------------------------
// per-edge attention logits -> exp  (wave per edge)
// ---------------------------------------------------------------------------
__global__ __launch_bounds__(256) void k_edge_attn(const float* __restrict__ qkv,
        const int* __restrict__ src, const int* __restrict__ dst,
        const float* __restrict__ base_attn, float* __restrict__ ex, int E) {
    int gw   = (blockIdx.x * 256 + threadIdx.x) >> 6;
    int lane = threadIdx.x & 63;
    if (gw >= E) return;
    int s = src[gw], d = dst[gw];
    const float* qs = qkv + (size_t)s * 384;
    const float* kd = qkv + (size_t)d * 384 + 128;
    float q0 = qs[lane] * SCALE, q1 = qs[lane + 64] * SCALE;
    float k0 = kd[lane],         k1 = kd[lane + 64];
    float t0 = q0 * k0, t1 = q1 * k1;
#pragma unroll
    for (int m = 1; m <= 16; m <<= 1) { t0 += __shfl_xor(t0, m); t1 += __shfl_xor(t1, m); }
    if (lane == 0) {
        ex[(size_t)gw * 4 + 0] = expf(t0 + base_attn[(size_t)gw * 4 + 0]);
        ex[(size_t)gw * 4 + 2] = expf(t1 + base_attn[(size_t)gw * 4 + 2]);
    } else if (lane == 32) {
        ex[(size_t)gw * 4 + 1] = expf(t0 + base_attn[(size_t)gw * 4 + 1]);
        ex[(size_t)gw * 4 + 3] = expf(t1 + base_attn[(size_t)gw * 4 + 3]);
    }
}

// ---------------------------------------------------------------------------
// softmax-normalize + aggregate v (wave per node, CSR over dst) -> f16 agg
// ---------------------------------------------------------------------------
__global__ __launch_bounds__(256) void k_agg(const float* __restrict__ qkv,
        const int* __restrict__ rowstart, const int* __restrict__ el,
        const int* __restrict__ src, const float* __restrict__ ex,
        _Float16* __restrict__ agg, int N) {
    int gw   = (blockIdx.x * 256 + threadIdx.x) >> 6;
    int lane = threadIdx.x & 63;
    if (gw >= N) return;
    int beg = rowstart[gw], end = rowstart[gw + 1];
    int h0 = lane >> 5;
    float s0 = 0.0f, s1 = 0.0f;
    for (int i = beg; i < end; ++i) {
        int e = el[i];
        s0 += ex[(size_t)e * 4 + h0];
        s1 += ex[(size_t)e * 4 + h0 + 2];
    }
    float inv0 = (s0 > 0.0f) ? 1.0f / s0 : 0.0f;
    float inv1 = (s1 > 0.0f) ? 1.0f / s1 : 0.0f;
    float a0 = 0.0f, a1 = 0.0f;
    for (int i = beg; i < end; ++i) {
        int e  = el[i];
        int sr = src[e];
        const float* v = qkv + (size_t)sr * 384 + 256;
        float w0 = ex[(size_t)e * 4 + h0]     * inv0;
        float w1 = ex[(size_t)e * 4 + h0 + 2] * inv1;
        a0 += w0 * v[lane];
        a1 += w1 * v[lane + 64];
    }
    agg[(size_t)gw * D + lane]      = (_Float16)a0;
    agg[(size_t)gw * D + lane + 64] = (_Float16)a1;
}

// ---------------------------------------------------------------------------
extern "C" void kernel_launch(void* const* d_in, const int* in_sizes, int n_in,
                              void* d_out, int out_size, void* d_ws, size_t ws_size,
                              hipStream_t stream) {
    const float* triplet_h = (const float*)d_in[0];
    const float* ple    = (const float*)d_in[1];
    const float* vpe    = (const float*)d_in[2];
    const float* sle    = (const float*)d_in[3];
    const float* dW1    = (const float*)d_in[4];
    const float* db1    = (const float*)d_in[5];
    const float* dW2    = (const float*)d_in[6];
    const float* db2    = (const float*)d_in[7];
    const float* tWin   = (const float*)d_in[8];
    const float* tbin   = (const float*)d_in[9];
    const float* tWout  = (const float*)d_in[10];
    const float* tbout  = (const float*)d_in[11];
    const float* pW1    = (const float*)d_in[12];
    const float* pb1    = (const float*)d_in[13];
    const float* pW2    = (const float*)d_in[14];
    const float* pb2    = (const float*)d_in[15];
    const float* ln1_g  = (const float*)d_in[16];
    const float* ln1_b  = (const float*)d_in[17];
    const float* qkv_W  = (const float*)d_in[18];
    const float* qkv_b  = (const float*)d_in[19];
    const float* rln_g  = (const float*)d_in[20];
    const float* rln_b  = (const float*)d_in[21];
    const float* res_W  = (const float*)d_in[22];
    const float* res_b  = (const float*)d_in[23];
    const float* fWin   = (const float*)d_in[24];
    const float* fbin   = (const float*)d_in[25];
    const float* fWout  = (const float*)d_in[26];
    const float* fbout  = (const float*)d_in[27];
    const int*   srcp   = (const int*)d_in[28];
    const int*   dstp   = (const int*)d_in[29];
    const int*   path   = (const int*)d_in[30];
    const int*   vp     = (const int*)d_in[31];
    const int*   sl     = (const int*)d_in[32];

    const int N = in_sizes[0] / D;
    const int E = in_sizes[28];

    char* ws = (char*)d_ws;
    size_t off = 0;
    auto alloc = [&](size_t bytes) -> void* {
        void* p = ws + off;
        off += (bytes + 255) & ~(size_t)255;
        return p;
    };
    float*     tab      = (float*)alloc((size_t)PP * N * DT * 4);
    float*     dist_tab = (float*)alloc(8 * H * 4);
    float*     base_attn= (float*)alloc((size_t)E * H * 4);
    int*       deg      = (int*)alloc((size_t)N * 4);
    int*       rowstart = (int*)alloc((size_t)(N + 1) * 4);
    int*       cursor   = (int*)alloc((size_t)N * 4);
    int*       el       = (int*)alloc((size_t)E * 4);
    _Float16*  hbuf     = (_Float16*)alloc((size_t)N * D * 2);
    float*     qkvbuf   = (float*)alloc((size_t)N * 384 * 4);
    float*     exbuf    = (float*)alloc((size_t)E * H * 4);
    _Float16*  aggbuf   = (_Float16*)alloc((size_t)N * D * 2);
    float*     bufA     = (float*)alloc((size_t)N * D * 4);
    float*     bufB     = (float*)alloc((size_t)N * D * 4);
    _Float16*  WtQ      = (_Float16*)alloc((size_t)NL * 384 * 128 * 2);
    _Float16*  WtR      = (_Float16*)alloc((size_t)NL * 128 * 128 * 2);
    _Float16*  Wt1      = (_Float16*)alloc((size_t)NL * 512 * 128 * 2);
    _Float16*  Wt2      = (_Float16*)alloc((size_t)NL * 128 * 512 * 2);
    if (off > ws_size) return;

    hipMemsetAsync(deg,    0, (size_t)N * 4, stream);
    hipMemsetAsync(cursor, 0, (size_t)N * 4, stream);

    // weight transpose-convert (f32 [K][C] -> f16 [C][K])
    WPrep wp;
    wp.src[0] = qkv_W;                wp.dst[0] = WtQ;               wp.K[0] = 128; wp.C[0] = 384;
    wp.src[1] = qkv_W + 128 * 384;    wp.dst[1] = WtQ + 384 * 128;   wp.K[1] = 128; wp.C[1] = 384;
    wp.src[2] = res_W;                wp.dst[2] = WtR;               wp.K[2] = 128; wp.C[2] = 128;
    wp.src[3] = res_W + 128 * 128;    wp.dst[3] = WtR + 128 * 128;   wp.K[3] = 128; wp.C[3] = 128;
    wp.src[4] = fWin;                 wp.dst[4] = Wt1;               wp.K[4] = 128; wp.C[4] = 512;
    wp.src[5] = fWin + 128 * 512;     wp.dst[5] = Wt1 + 512 * 128;   wp.K[5] = 128; wp.C[5] = 512;
    wp.src[6] = fWout;                wp.dst[6] = Wt2;               wp.K[6] = 512; wp.C[6] = 128;
    wp.src[7] = fWout + 512 * 128;    wp.dst[7] = Wt2 + 128 * 512;   wp.K[7] = 512; wp.C[7] = 128;
    k_wprep<<<dim3(256, 8), 256, 0, stream>>>(wp);

    k_dist_tab<<<1, 256, 0, stream>>>(ple, vpe, sle, dW1, db1, dW2, db2, dist_tab);
    k_tab<<<(N + 63) / 64, 256, 0, stream>>>(triplet_h, tWin, tbin, tWout, tbout, tab, N);
    k_edge_pre<<<(E + 255) / 256, 256, 0, stream>>>(path, vp, sl, tab, dist_tab,
                                                    pW1, pb1, pW2, pb2, base_attn, E, N);
    k_count<<<(E + 255) / 256, 256, 0, stream>>>(dstp, deg, E);
    k_scan<<<1, 1024, 0, stream>>>(deg, rowstart, N);
    k_scatter<<<(E + 255) / 256, 256, 0, stream>>>(dstp, rowstart, cursor, el, E);

    hipMemcpyAsync(bufA, triplet_h, (size_t)N * D * 4, hipMemcpyDeviceToDevice, stream);

    for (int l = 0; l < NL; ++l) {
        k_ln<<<(N + 3) / 4, 256, 0, stream>>>(bufA, ln1_g + l * D, ln1_b + l * D, hbuf, N);
        k_qkv_mfma<<<(N + 63) / 64, 256, 0, stream>>>(hbuf, WtQ + (size_t)l * 384 * 128,
                                                      qkv_b + l * 384, qkvbuf, N);
        k_edge_attn<<<(E + 3) / 4, 256, 0, stream>>>(qkvbuf, srcp, dstp, base_attn, exbuf, E);
        k_agg<<<(N + 3) / 4, 256, 0, stream>>>(qkvbuf, rowstart, el, srcp, exbuf, aggbuf, N);
        k_res_mfma<<<(N + 63) / 64, 256, 0, stream>>>(aggbuf, WtR + (size_t)l * 128 * 128,
                                                      res_b + l * D, bufA, bufB, N);
        k_ln<<<(N + 3) / 4, 256, 0, stream>>>(bufB, rln_g + l * D, rln_b + l * D, hbuf, N);
        k_ffn_mfma<<<(N + 63) / 64, 256, 0, stream>>>(hbuf, bufB,
                                                      Wt1 + (size_t)l * 512 * 128, fbin + l * FF,
                                                      Wt2 + (size_t)l * 128 * 512, fbout + l * D,
                                                      bufA, N);
    }

    hipMemcpyAsync(d_out, bufA, (size_t)N * D * 4, hipMemcpyDeviceToDevice, stream);
}

// Round 9
// 1118.589 us; speedup vs baseline: 1.4263x; 1.1250x over previous
//
#include <hip/hip_runtime.h>
#include <math.h>

#define D   128
#define H   4
#define PP  5
#define DT  32
#define FF  512
#define NL  2
#define SCALE 0.08838834764831845f

typedef _Float16 f16x8 __attribute__((ext_vector_type(8)));
typedef float    f32x4 __attribute__((ext_vector_type(4)));

__device__ __forceinline__ float gelu(float x) {
    return 0.5f * x * (1.0f + erff(x * 0.7071067811865476f));
}

__device__ __forceinline__ f16x8 f16x8_zero() {
    f16x8 v;
#pragma unroll
    for (int j = 0; j < 8; ++j) v[j] = (_Float16)0.0f;
    return v;
}

// ---------------------------------------------------------------------------
// weight prep: transpose-convert f32 W[K][C] -> f16 Wt[C][K]  (18 matrices)
// grid MUST cover max K*C = 512*128 = 65536 -> 256 blocks x 256 threads.
// ---------------------------------------------------------------------------
#define NWP 18
struct WPrep {
    const float* src[NWP];
    _Float16*    dst[NWP];
    int K[NWP], C[NWP];
};

__global__ __launch_bounds__(256) void k_wprep(WPrep p) {
    int m = blockIdx.y;
    int n = blockIdx.x * 256 + threadIdx.x;
    int K = p.K[m], C = p.C[m];
    if (n >= K * C) return;
    int c = n / K, k = n - c * K;
    p.dst[m][n] = (_Float16)p.src[m][(size_t)k * C + c];
}

// ---------------------------------------------------------------------------
// dist_attn table: 8 possible pf vectors -> gelu(pf@dW1+db1)@dW2+db2  (8 x H)
// ---------------------------------------------------------------------------
__global__ __launch_bounds__(256) void k_dist_tab(
    const float* __restrict__ ple, const float* __restrict__ vpe, const float* __restrict__ sle,
    const float* __restrict__ dW1, const float* __restrict__ db1,
    const float* __restrict__ dW2, const float* __restrict__ db2,
    float* __restrict__ dist_tab)
{
    __shared__ float pf[8][D];
    __shared__ float hid[8][D];
    int t = threadIdx.x;
    for (int i = t; i < 8 * D; i += 256) {
        int r = i >> 7, c = i & 127;
        float v;
        if (r < 6)      v = ple[r * D + c];
        else if (r == 6) v = vpe[c];
        else             v = sle[c];
        pf[r][c] = v;
    }
    __syncthreads();
    for (int i = t; i < 8 * D; i += 256) {
        int r = i >> 7, c = i & 127;
        float s = db1[c];
        for (int k = 0; k < D; ++k) s += pf[r][k] * dW1[k * D + c];
        hid[r][c] = gelu(s);
    }
    __syncthreads();
    if (t < 8 * H) {
        int r = t >> 2, h = t & 3;
        float s = db2[h];
        for (int k = 0; k < D; ++k) s += hid[r][k] * dW2[k * H + h];
        dist_tab[r * H + h] = s;
    }
}

// ---------------------------------------------------------------------------
// tab (MFMA): tab[i][n][:] = gelu(X[n]@tWin[i]+tbin[i]) @ tWout[i] + tbout[i]
// block: 64 rows, 4 waves. GEMM1 K=128, GEMM2 K=32 (1 MFMA).
// Wave-private LDS stripe between the two (k_ffn_mfma-validated pattern).
// ---------------------------------------------------------------------------
__global__ __launch_bounds__(256) void k_tab_mfma(
    const float* __restrict__ X,
    const _Float16* __restrict__ Wt1,  // [PP][DT][128]  (tWin^T)
    const float* __restrict__ tbin,
    const _Float16* __restrict__ Wt2,  // [PP][DT][DT]   (tWout^T)
    const float* __restrict__ tbout,
    float* __restrict__ tab, int N)
{
    __shared__ _Float16 Ah[64][136];       // f16 X tile, stride 272B
    __shared__ _Float16 hidS[4][16][40];   // per-wave 16x32 stripe, stride 80B
    int t = threadIdx.x;
    int n0 = blockIdx.x * 64;
#pragma unroll
    for (int i = 0; i < 4; ++i) {
        int flat = t + i * 256;
        int r = flat >> 4, c = flat & 15;
        f16x8 v = f16x8_zero();
        if (n0 + r < N) {
            const float* xp = X + (size_t)(n0 + r) * D + c * 8;
            float4 x0 = *(const float4*)xp;
            float4 x1 = *(const float4*)(xp + 4);
            v[0] = (_Float16)x0.x; v[1] = (_Float16)x0.y;
            v[2] = (_Float16)x0.z; v[3] = (_Float16)x0.w;
            v[4] = (_Float16)x1.x; v[5] = (_Float16)x1.y;
            v[6] = (_Float16)x1.z; v[7] = (_Float16)x1.w;
        }
        *(f16x8*)&Ah[r][c * 8] = v;
    }
    __syncthreads();
    int w = t >> 6, lane = t & 63;
    int rt0 = w * 16, lr = lane & 15, lg = lane >> 4;
    f16x8 a1[4];
#pragma unroll
    for (int kk = 0; kk < 4; ++kk)
        a1[kk] = *(const f16x8*)&Ah[rt0 + lr][kk * 32 + lg * 8];

    for (int i = 0; i < PP; ++i) {
        // GEMM1: hidden[16 rows][32 cols] for this wave
#pragma unroll
        for (int ct = 0; ct < 2; ++ct) {
            int col = ct * 16 + lr;
            f32x4 c1 = {0.f, 0.f, 0.f, 0.f};
#pragma unroll
            for (int kk = 0; kk < 4; ++kk) {
                f16x8 b = *(const f16x8*)&Wt1[((size_t)i * DT + col) * 128 + kk * 32 + lg * 8];
                c1 = __builtin_amdgcn_mfma_f32_16x16x32_f16(a1[kk], b, c1, 0, 0, 0);
            }
            float bb = tbin[i * DT + col];
#pragma unroll
            for (int j = 0; j < 4; ++j)
                hidS[w][lg * 4 + j][col] = (_Float16)gelu(c1[j] + bb);
        }
        // GEMM2: K=32 -> single MFMA per 16-col tile (wave-private stripe, in-order LDS)
        f16x8 a2 = *(const f16x8*)&hidS[w][lr][lg * 8];
#pragma unroll
        for (int ct = 0; ct < 2; ++ct) {
            int col = ct * 16 + lr;
            f32x4 c2 = {0.f, 0.f, 0.f, 0.f};
            f16x8 b2 = *(const f16x8*)&Wt2[((size_t)i * DT + col) * DT + lg * 8];
            c2 = __builtin_amdgcn_mfma_f32_16x16x32_f16(a2, b2, c2, 0, 0, 0);
            float bb = tbout[i * DT + col];
#pragma unroll
            for (int j = 0; j < 4; ++j) {
                int row = n0 + rt0 + lg * 4 + j;
                if (row < N) tab[((size_t)i * N + row) * DT + col] = c2[j] + bb;
            }
        }
    }
}

// ---------------------------------------------------------------------------
// per-edge: path gather-mean -> small MLP -> + dist_tab lookup
// ---------------------------------------------------------------------------
__global__ __launch_bounds__(256) void k_edge_pre(
    const int* __restrict__ path, const int* __restrict__ vp, const int* __restrict__ sl,
    const float* __restrict__ tab, const float* __restrict__ dist_tab,
    const float* __restrict__ pW1, const float* __restrict__ pb1,
    const float* __restrict__ pW2, const float* __restrict__ pb2,
    float* __restrict__ base_attn, int E, int N)
{
    __shared__ float W1t[DT][DT];
    __shared__ float W2s[DT][H];
    __shared__ float b1s[DT];
    __shared__ float b2s[H];
    __shared__ float dts[8][H];
    int t = threadIdx.x;
    for (int i = t; i < DT * DT; i += 256) {
        int k = i >> 5, c = i & 31;
        W1t[c][k] = pW1[i];
    }
    if (t < DT * H) W2s[t >> 2][t & 3] = pW2[t];
    if (t < DT) b1s[t] = pb1[t];
    if (t < H)  b2s[t] = pb2[t];
    if (t < 32) dts[t >> 2][t & 3] = dist_tab[t];
    __syncthreads();
    int e = blockIdx.x * 256 + t;
    if (e >= E) return;
    int pl = 0;
    float acc[DT];
#pragma unroll
    for (int c = 0; c < DT; ++c) acc[c] = 0.0f;
#pragma unroll
    for (int i = 0; i < PP; ++i) {
        int p = path[(size_t)e * PP + i];
        if (p < -99) p = -1;
        if (p >= 0) {
            ++pl;
            const float* row = tab + ((size_t)i * N + p) * DT;
#pragma unroll
            for (int c4 = 0; c4 < 8; ++c4) {
                float4 v = *(const float4*)(row + c4 * 4);
                acc[c4 * 4 + 0] += v.x; acc[c4 * 4 + 1] += v.y;
                acc[c4 * 4 + 2] += v.z; acc[c4 * 4 + 3] += v.w;
            }
        }
    }
    float inv = 1.0f / (float)(pl > 0 ? pl : 1);
#pragma unroll
    for (int c = 0; c < DT; ++c) acc[c] *= inv;
    float o0 = b2s[0], o1 = b2s[1], o2 = b2s[2], o3 = b2s[3];
    for (int c = 0; c < DT; ++c) {
        float s = b1s[c];
#pragma unroll
        for (int k4 = 0; k4 < 8; ++k4) {
            float4 w = *(const float4*)&W1t[c][k4 * 4];
            s += acc[k4 * 4 + 0] * w.x + acc[k4 * 4 + 1] * w.y +
                 acc[k4 * 4 + 2] * w.z + acc[k4 * 4 + 3] * w.w;
        }
        float hv = gelu(s);
        o0 += hv * W2s[c][0]; o1 += hv * W2s[c][1];
        o2 += hv * W2s[c][2]; o3 += hv * W2s[c][3];
    }
    int se = (sl[e] == 1) ? 7 : ((vp[e] == 1) ? 6 : pl);
    float4 ov = make_float4(o0 + dts[se][0], o1 + dts[se][1],
                            o2 + dts[se][2], o3 + dts[se][3]);
    *(float4*)(base_attn + (size_t)e * 4) = ov;
}

// ---------------------------------------------------------------------------
// CSR build over dst
// ---------------------------------------------------------------------------
__global__ void k_count(const int* __restrict__ dst, int* __restrict__ deg, int E) {
    int e = blockIdx.x * 256 + threadIdx.x;
    if (e < E) atomicAdd(&deg[dst[e]], 1);
}

__global__ __launch_bounds__(1024) void k_scan(const int* __restrict__ deg,
                                               int* __restrict__ rowstart, int N) {
    __shared__ int sdata[1024];
    __shared__ int soff;
    int t = threadIdx.x;
    if (t == 0) soff = 0;
    for (int base = 0; base < N; base += 1024) {
        int v = (base + t < N) ? deg[base + t] : 0;
        __syncthreads();
        sdata[t] = v;
        __syncthreads();
        for (int off = 1; off < 1024; off <<= 1) {
            int x = (t >= off) ? sdata[t - off] : 0;
            __syncthreads();
            sdata[t] += x;
            __syncthreads();
        }
        int incl  = sdata[t];
        int total = sdata[1023];
        if (base + t < N) rowstart[base + t] = soff + incl - v;
        __syncthreads();
        if (t == 0) soff += total;
    }
    __syncthreads();
    if (t == 0) rowstart[N] = soff;
}

__global__ void k_scatter(const int* __restrict__ dst, const int* __restrict__ rowstart,
                          int* __restrict__ cursor, int* __restrict__ el, int E) {
    int e = blockIdx.x * 256 + threadIdx.x;
    if (e >= E) return;
    int d = dst[e];
    int pos = atomicAdd(&cursor[d], 1);
    el[rowstart[d] + pos] = e;
}

// ---------------------------------------------------------------------------
// LayerNorm: one wave per row of 128, writes f16 for MFMA consumers
// ---------------------------------------------------------------------------
__global__ __launch_bounds__(256) void k_ln(const float* __restrict__ X, const float* __restrict__ g,
                                            const float* __restrict__ b, _Float16* __restrict__ out, int N) {
    int gw   = (blockIdx.x * 256 + threadIdx.x) >> 6;
    int lane = threadIdx.x & 63;
    if (gw >= N) return;
    const float* x = X + (size_t)gw * D;
    float a0 = x[lane], a1 = x[lane + 64];
    float s = a0 + a1;
#pragma unroll
    for (int m = 1; m < 64; m <<= 1) s += __shfl_xor(s, m);
    float mu = s * (1.0f / 128.0f);
    float d0 = a0 - mu, d1 = a1 - mu;
    float v = d0 * d0 + d1 * d1;
#pragma unroll
    for (int m = 1; m < 64; m <<= 1) v += __shfl_xor(v, m);
    float r = rsqrtf(v * (1.0f / 128.0f) + 1e-5f);
    _Float16* o = out + (size_t)gw * D;
    o[lane]      = (_Float16)(d0 * r * g[lane]      + b[lane]);
    o[lane + 64] = (_Float16)(d1 * r * g[lane + 64] + b[lane + 64]);
}

// ---------------------------------------------------------------------------
// MFMA fragment conventions (gfx950 16x16x32, HW-verified layout):
//   A-frag: lane l holds A[m=l&15][k=(l>>4)*8 + 0..7]   (contig 16B)
//   B-frag: lane l holds B[k=(l>>4)*8+j][n=l&15] -> from Wt[n][k] contig 16B
//   C/D   : col = l&15, row = (l>>4)*4 + reg
// ---------------------------------------------------------------------------

// qkv GEMM: C[N][384] = A[N][128] @ W[128][384] + bias. block 64 rows, 4 waves
__global__ __launch_bounds__(256) void k_qkv_mfma(
    const _Float16* __restrict__ Hin, const _Float16* __restrict__ Wt, // [384][128]
    const float* __restrict__ bias, float* __restrict__ C, int N)
{
    __shared__ _Float16 Ah[64][136];   // pad 8 f16: row stride 272B -> conflict-free frags
    int t = threadIdx.x;
    int n0 = blockIdx.x * 64;
#pragma unroll
    for (int i = 0; i < 4; ++i) {
        int flat = t + i * 256;
        int r = flat >> 4, c = flat & 15;
        f16x8 v = f16x8_zero();
        if (n0 + r < N) v = *(const f16x8*)&Hin[(size_t)(n0 + r) * D + c * 8];
        *(f16x8*)&Ah[r][c * 8] = v;
    }
    __syncthreads();
    int w = t >> 6, lane = t & 63;
    int rt0 = w * 16, lr = lane & 15, lg = lane >> 4;
    f16x8 a1[4];
#pragma unroll
    for (int kk = 0; kk < 4; ++kk)
        a1[kk] = *(const f16x8*)&Ah[rt0 + lr][kk * 32 + lg * 8];
#pragma unroll 4
    for (int ct = 0; ct < 24; ++ct) {
        int col = ct * 16 + lr;
        f32x4 acc = {0.f, 0.f, 0.f, 0.f};
#pragma unroll
        for (int kk = 0; kk < 4; ++kk) {
            f16x8 b = *(const f16x8*)&Wt[(size_t)col * 128 + kk * 32 + lg * 8];
            acc = __builtin_amdgcn_mfma_f32_16x16x32_f16(a1[kk], b, acc, 0, 0, 0);
        }
        float bb = bias[col];
#pragma unroll
        for (int i = 0; i < 4; ++i) {
            int row = n0 + rt0 + lg * 4 + i;
            if (row < N) C[(size_t)row * 384 + col] = acc[i] + bb;
        }
    }
}

// res GEMM: Out = resid + Agg @ res_W + bias. block 64 rows, 4 waves
__global__ __launch_bounds__(256) void k_res_mfma(
    const _Float16* __restrict__ Agg, const _Float16* __restrict__ Wt, // [128][128]
    const float* __restrict__ bias, const float* __restrict__ resid,
    float* __restrict__ Out, int N)
{
    __shared__ _Float16 Ah[64][136];
    int t = threadIdx.x;
    int n0 = blockIdx.x * 64;
#pragma unroll
    for (int i = 0; i < 4; ++i) {
        int flat = t + i * 256;
        int r = flat >> 4, c = flat & 15;
        f16x8 v = f16x8_zero();
        if (n0 + r < N) v = *(const f16x8*)&Agg[(size_t)(n0 + r) * D + c * 8];
        *(f16x8*)&Ah[r][c * 8] = v;
    }
    __syncthreads();
    int w = t >> 6, lane = t & 63;
    int rt0 = w * 16, lr = lane & 15, lg = lane >> 4;
    f16x8 a1[4];
#pragma unroll
    for (int kk = 0; kk < 4; ++kk)
        a1[kk] = *(const f16x8*)&Ah[rt0 + lr][kk * 32 + lg * 8];
#pragma unroll
    for (int ct = 0; ct < 8; ++ct) {
        int col = ct * 16 + lr;
        f32x4 acc = {0.f, 0.f, 0.f, 0.f};
#pragma unroll
        for (int kk = 0; kk < 4; ++kk) {
            f16x8 b = *(const f16x8*)&Wt[(size_t)col * 128 + kk * 32 + lg * 8];
            acc = __builtin_amdgcn_mfma_f32_16x16x32_f16(a1[kk], b, acc, 0, 0, 0);
        }
        float bb = bias[col];
#pragma unroll
        for (int i = 0; i < 4; ++i) {
            int row = n0 + rt0 + lg * 4 + i;
            if (row < N) {
                size_t o = (size_t)row * D + col;
                Out[o] = resid[o] + acc[i] + bb;
            }
        }
    }
}

// fused FFN: Out = Xres + gelu(Hin@Win+bin)@Wout+bout. block 64 rows, 4 waves
__global__ __launch_bounds__(256) void k_ffn_mfma(
    const _Float16* __restrict__ Hin, const float* __restrict__ Xres,
    const _Float16* __restrict__ Wt1,  // [512][128] (Win^T)
    const float* __restrict__ bin,
    const _Float16* __restrict__ Wt2,  // [128][512] (Wout^T)
    const float* __restrict__ bout,
    float* __restrict__ Out, int N)
{
    __shared__ _Float16 Ah[64][136];
    __shared__ _Float16 hid[64][264];  // 256-col chunk + 8 pad (row stride 528B)
    int t = threadIdx.x;
    int n0 = blockIdx.x * 64;
#pragma unroll
    for (int i = 0; i < 4; ++i) {
        int flat = t + i * 256;
        int r = flat >> 4, c = flat & 15;
        f16x8 v = f16x8_zero();
        if (n0 + r < N) v = *(const f16x8*)&Hin[(size_t)(n0 + r) * D + c * 8];
        *(f16x8*)&Ah[r][c * 8] = v;
    }
    __syncthreads();
    int w = t >> 6, lane = t & 63;
    int rt0 = w * 16, lr = lane & 15, lg = lane >> 4;
    f16x8 a1[4];
#pragma unroll
    for (int kk = 0; kk < 4; ++kk)
        a1[kk] = *(const f16x8*)&Ah[rt0 + lr][kk * 32 + lg * 8];

    f32x4 acc2[8];
#pragma unroll
    for (int i = 0; i < 8; ++i) acc2[i] = (f32x4){0.f, 0.f, 0.f, 0.f};

    for (int ch = 0; ch < 2; ++ch) {
#pragma unroll 4
        for (int ct = 0; ct < 16; ++ct) {
            int hc = ch * 256 + ct * 16 + lr;
            f32x4 c1 = {0.f, 0.f, 0.f, 0.f};
#pragma unroll
            for (int kk = 0; kk < 4; ++kk) {
                f16x8 b = *(const f16x8*)&Wt1[(size_t)hc * 128 + kk * 32 + lg * 8];
                c1 = __builtin_amdgcn_mfma_f32_16x16x32_f16(a1[kk], b, c1, 0, 0, 0);
            }
            float bb = bin[hc];
#pragma unroll
            for (int i = 0; i < 4; ++i) {
                float v = gelu(c1[i] + bb);
                hid[rt0 + lg * 4 + i][ct * 16 + lr] = (_Float16)v;
            }
        }
#pragma unroll 2
        for (int kk2 = 0; kk2 < 8; ++kk2) {
            f16x8 a2 = *(const f16x8*)&hid[rt0 + lr][kk2 * 32 + lg * 8];
            int gk = ch * 256 + kk2 * 32 + lg * 8;
#pragma unroll
            for (int ct2 = 0; ct2 < 8; ++ct2) {
                f16x8 b2 = *(const f16x8*)&Wt2[(size_t)(ct2 * 16 + lr) * 512 + gk];
                acc2[ct2] = __builtin_amdgcn_mfma_f32_16x16x32_f16(a2, b2, acc2[ct2], 0, 0, 0);
            }
        }
    }
#pragma unroll
    for (int ct2 = 0; ct2 < 8; ++ct2) {
        int col = ct2 * 16 + lr;
        float bb = bout[col];
#pragma unroll
        for (int i = 0; i < 4; ++i) {
            int row = n0 + rt0 + lg * 4 + i;
            if (row < N) {
                size_t o = (size_t)row * D + col;
                Out[o] = Xres[o] + acc2[ct2][i] + bb;
            }
        }
    }
}

// ---------------------------------------------------------------------------
// per-edge attention logits -> exp  (wave per edge)
// ---------------------------------------------------------------------------
__global__ __launch_bounds__(256) void k_edge_attn(const float* __restrict__ qkv,
        const int* __restrict__ src, const int* __restrict__ dst,
        const float* __restrict__ base_attn, float* __restrict__ ex, int E) {
    int gw   = (blockIdx.x * 256 + threadIdx.x) >> 6;
    int lane = threadIdx.x & 63;
    if (gw >= E) return;
    int s = src[gw], d = dst[gw];
    const float* qs = qkv + (size_t)s * 384;
    const float* kd = qkv + (size_t)d * 384 + 128;
    float q0 = qs[lane] * SCALE, q1 = qs[lane + 64] * SCALE;
    float k0 = kd[lane],         k1 = kd[lane + 64];
    float t0 = q0 * k0, t1 = q1 * k1;
#pragma unroll
    for (int m = 1; m <= 16; m <<= 1) { t0 += __shfl_xor(t0, m); t1 += __shfl_xor(t1, m); }
    if (lane == 0) {
        ex[(size_t)gw * 4 + 0] = expf(t0 + base_attn[(size_t)gw * 4 + 0]);
        ex[(size_t)gw * 4 + 2] = expf(t1 + base_attn[(size_t)gw * 4 + 2]);
    } else if (lane == 32) {
        ex[(size_t)gw * 4 + 1] = expf(t0 + base_attn[(size_t)gw * 4 + 1]);
        ex[(size_t)gw * 4 + 3] = expf(t1 + base_attn[(size_t)gw * 4 + 3]);
    }
}

// ---------------------------------------------------------------------------
// softmax-normalize + aggregate v (wave per node, CSR over dst) -> f16 agg
// ---------------------------------------------------------------------------
__global__ __launch_bounds__(256) void k_agg(const float* __restrict__ qkv,
        const int* __restrict__ rowstart, const int* __restrict__ el,
        const int* __restrict__ src, const float* __restrict__ ex,
        _Float16* __restrict__ agg, int N) {
    int gw   = (blockIdx.x * 256 + threadIdx.x) >> 6;
    int lane = threadIdx.x & 63;
    if (gw >= N) return;
    int beg = rowstart[gw], end = rowstart[gw + 1];
    int h0 = lane >> 5;
    float s0 = 0.0f, s1 = 0.0f;
    for (int i = beg; i < end; ++i) {
        int e = el[i];
        s0 += ex[(size_t)e * 4 + h0];
        s1 += ex[(size_t)e * 4 + h0 + 2];
    }
    float inv0 = (s0 > 0.0f) ? 1.0f / s0 : 0.0f;
    float inv1 = (s1 > 0.0f) ? 1.0f / s1 : 0.0f;
    float a0 = 0.0f, a1 = 0.0f;
    for (int i = beg; i < end; ++i) {
        int e  = el[i];
        int sr = src[e];
        const float* v = qkv + (size_t)sr * 384 + 256;
        float w0 = ex[(size_t)e * 4 + h0]     * inv0;
        float w1 = ex[(size_t)e * 4 + h0 + 2] * inv1;
        a0 += w0 * v[lane];
        a1 += w1 * v[lane + 64];
    }
    agg[(size_t)gw * D + lane]      = (_Float16)a0;
    agg[(size_t)gw * D + lane + 64] = (_Float16)a1;
}

// ---------------------------------------------------------------------------
extern "C" void kernel_launch(void* const* d_in, const int* in_sizes, int n_in,
                              void* d_out, int out_size, void* d_ws, size_t ws_size,
                              hipStream_t stream) {
    const float* triplet_h = (const float*)d_in[0];
    const float* ple    = (const float*)d_in[1];
    const float* vpe    = (const float*)d_in[2];
    const float* sle    = (const float*)d_in[3];
    const float* dW1    = (const float*)d_in[4];
    const float* db1    = (const float*)d_in[5];
    const float* dW2    = (const float*)d_in[6];
    const float* db2    = (const float*)d_in[7];
    const float* tWin   = (const float*)d_in[8];
    const float* tbin   = (const float*)d_in[9];
    const float* tWout  = (const float*)d_in[10];
    const float* tbout  = (const float*)d_in[11];
    const float* pW1    = (const float*)d_in[12];
    const float* pb1    = (const float*)d_in[13];
    const float* pW2    = (const float*)d_in[14];
    const float* pb2    = (const float*)d_in[15];
    const float* ln1_g  = (const float*)d_in[16];
    const float* ln1_b  = (const float*)d_in[17];
    const float* qkv_W  = (const float*)d_in[18];
    const float* qkv_b  = (const float*)d_in[19];
    const float* rln_g  = (const float*)d_in[20];
    const float* rln_b  = (const float*)d_in[21];
    const float* res_W  = (const float*)d_in[22];
    const float* res_b  = (const float*)d_in[23];
    const float* fWin   = (const float*)d_in[24];
    const float* fbin   = (const float*)d_in[25];
    const float* fWout  = (const float*)d_in[26];
    const float* fbout  = (const float*)d_in[27];
    const int*   srcp   = (const int*)d_in[28];
    const int*   dstp   = (const int*)d_in[29];
    const int*   path   = (const int*)d_in[30];
    const int*   vp     = (const int*)d_in[31];
    const int*   sl     = (const int*)d_in[32];

    const int N = in_sizes[0] / D;
    const int E = in_sizes[28];

    char* ws = (char*)d_ws;
    size_t off = 0;
    auto alloc = [&](size_t bytes) -> void* {
        void* p = ws + off;
        off += (bytes + 255) & ~(size_t)255;
        return p;
    };
    float*     tab      = (float*)alloc((size_t)PP * N * DT * 4);
    float*     dist_tab = (float*)alloc(8 * H * 4);
    float*     base_attn= (float*)alloc((size_t)E * H * 4);
    int*       deg      = (int*)alloc((size_t)N * 4);
    int*       rowstart = (int*)alloc((size_t)(N + 1) * 4);
    int*       cursor   = (int*)alloc((size_t)N * 4);
    int*       el       = (int*)alloc((size_t)E * 4);
    _Float16*  hbuf     = (_Float16*)alloc((size_t)N * D * 2);
    float*     qkvbuf   = (float*)alloc((size_t)N * 384 * 4);
    float*     exbuf    = (float*)alloc((size_t)E * H * 4);
    _Float16*  aggbuf   = (_Float16*)alloc((size_t)N * D * 2);
    float*     bufA     = (float*)alloc((size_t)N * D * 4);
    float*     bufB     = (float*)alloc((size_t)N * D * 4);
    _Float16*  WtQ      = (_Float16*)alloc((size_t)NL * 384 * 128 * 2);
    _Float16*  WtR      = (_Float16*)alloc((size_t)NL * 128 * 128 * 2);
    _Float16*  Wt1      = (_Float16*)alloc((size_t)NL * 512 * 128 * 2);
    _Float16*  Wt2      = (_Float16*)alloc((size_t)NL * 128 * 512 * 2);
    _Float16*  WtTin    = (_Float16*)alloc((size_t)PP * DT * 128 * 2);
    _Float16*  WtTout   = (_Float16*)alloc((size_t)PP * DT * DT * 2);
    if (off > ws_size) return;

    hipMemsetAsync(deg,    0, (size_t)N * 4, stream);
    hipMemsetAsync(cursor, 0, (size_t)N * 4, stream);

    // weight transpose-convert (f32 [K][C] -> f16 [C][K])
    WPrep wp;
    wp.src[0] = qkv_W;                wp.dst[0] = WtQ;               wp.K[0] = 128; wp.C[0] = 384;
    wp.src[1] = qkv_W + 128 * 384;    wp.dst[1] = WtQ + 384 * 128;   wp.K[1] = 128; wp.C[1] = 384;
    wp.src[2] = res_W;                wp.dst[2] = WtR;               wp.K[2] = 128; wp.C[2] = 128;
    wp.src[3] = res_W + 128 * 128;    wp.dst[3] = WtR + 128 * 128;   wp.K[3] = 128; wp.C[3] = 128;
    wp.src[4] = fWin;                 wp.dst[4] = Wt1;               wp.K[4] = 128; wp.C[4] = 512;
    wp.src[5] = fWin + 128 * 512;     wp.dst[5] = Wt1 + 512 * 128;   wp.K[5] = 128; wp.C[5] = 512;
    wp.src[6] = fWout;                wp.dst[6] = Wt2;               wp.K[6] = 512; wp.C[6] = 128;
    wp.src[7] = fWout + 512 * 128;    wp.dst[7] = Wt2 + 128 * 512;   wp.K[7] = 512; wp.C[7] = 128;
    for (int i = 0; i < PP; ++i) {
        wp.src[8 + i]  = tWin  + (size_t)i * 128 * DT;
        wp.dst[8 + i]  = WtTin + (size_t)i * DT * 128;
        wp.K[8 + i] = 128; wp.C[8 + i] = DT;
        wp.src[13 + i] = tWout  + (size_t)i * DT * DT;
        wp.dst[13 + i] = WtTout + (size_t)i * DT * DT;
        wp.K[13 + i] = DT; wp.C[13 + i] = DT;
    }
    k_wprep<<<dim3(256, NWP), 256, 0, stream>>>(wp);

    k_dist_tab<<<1, 256, 0, stream>>>(ple, vpe, sle, dW1, db1, dW2, db2, dist_tab);
    k_tab_mfma<<<(N + 63) / 64, 256, 0, stream>>>(triplet_h, WtTin, tbin, WtTout, tbout, tab, N);
    k_edge_pre<<<(E + 255) / 256, 256, 0, stream>>>(path, vp, sl, tab, dist_tab,
                                                    pW1, pb1, pW2, pb2, base_attn, E, N);
    k_count<<<(E + 255) / 256, 256, 0, stream>>>(dstp, deg, E);
    k_scan<<<1, 1024, 0, stream>>>(deg, rowstart, N);
    k_scatter<<<(E + 255) / 256, 256, 0, stream>>>(dstp, rowstart, cursor, el, E);

    hipMemcpyAsync(bufA, triplet_h, (size_t)N * D * 4, hipMemcpyDeviceToDevice, stream);

    for (int l = 0; l < NL; ++l) {
        k_ln<<<(N + 3) / 4, 256, 0, stream>>>(bufA, ln1_g + l * D, ln1_b + l * D, hbuf, N);
        k_qkv_mfma<<<(N + 63) / 64, 256, 0, stream>>>(hbuf, WtQ + (size_t)l * 384 * 128,
                                                      qkv_b + l * 384, qkvbuf, N);
        k_edge_attn<<<(E + 3) / 4, 256, 0, stream>>>(qkvbuf, srcp, dstp, base_attn, exbuf, E);
        k_agg<<<(N + 3) / 4, 256, 0, stream>>>(qkvbuf, rowstart, el, srcp, exbuf, aggbuf, N);
        k_res_mfma<<<(N + 63) / 64, 256, 0, stream>>>(aggbuf, WtR + (size_t)l * 128 * 128,
                                                      res_b + l * D, bufA, bufB, N);
        k_ln<<<(N + 3) / 4, 256, 0, stream>>>(bufB, rln_g + l * D, rln_b + l * D, hbuf, N);
        k_ffn_mfma<<<(N + 63) / 64, 256, 0, stream>>>(hbuf, bufB,
                                                      Wt1 + (size_t)l * 512 * 128, fbin + l * FF,
                                                      Wt2 + (size_t)l * 128 * 512, fbout + l * D,
                                                      bufA, N);
    }

    hipMemcpyAsync(d_out, bufA, (size_t)N * D * 4, hipMemcpyDeviceToDevice, stream);
}

// Round 10
// 786.741 us; speedup vs baseline: 2.0279x; 1.4218x over previous
//
#include <hip/hip_runtime.h>
#include <math.h>

#define D   128
#define H   4
#define PP  5
#define DT  32
#define FF  512
#define NL  2
#define SCALE 0.08838834764831845f

typedef _Float16 f16x8 __attribute__((ext_vector_type(8)));
typedef _Float16 f16x2 __attribute__((ext_vector_type(2)));
typedef float    f32x4 __attribute__((ext_vector_type(4)));

__device__ __forceinline__ float gelu(float x) {
    return 0.5f * x * (1.0f + erff(x * 0.7071067811865476f));
}

__device__ __forceinline__ f16x8 f16x8_zero() {
    f16x8 v;
#pragma unroll
    for (int j = 0; j < 8; ++j) v[j] = (_Float16)0.0f;
    return v;
}

// ---------------------------------------------------------------------------
// weight prep: transpose-convert f32 W[K][C] -> f16 Wt[C][K]  (18 matrices)
// grid MUST cover max K*C = 512*128 = 65536 -> 256 blocks x 256 threads.
// ---------------------------------------------------------------------------
#define NWP 18
struct WPrep {
    const float* src[NWP];
    _Float16*    dst[NWP];
    int K[NWP], C[NWP];
};

__global__ __launch_bounds__(256) void k_wprep(WPrep p) {
    int m = blockIdx.y;
    int n = blockIdx.x * 256 + threadIdx.x;
    int K = p.K[m], C = p.C[m];
    if (n >= K * C) return;
    int c = n / K, k = n - c * K;
    p.dst[m][n] = (_Float16)p.src[m][(size_t)k * C + c];
}

// ---------------------------------------------------------------------------
// dist_attn table: 8 possible pf vectors -> gelu(pf@dW1+db1)@dW2+db2  (8 x H)
// ---------------------------------------------------------------------------
__global__ __launch_bounds__(256) void k_dist_tab(
    const float* __restrict__ ple, const float* __restrict__ vpe, const float* __restrict__ sle,
    const float* __restrict__ dW1, const float* __restrict__ db1,
    const float* __restrict__ dW2, const float* __restrict__ db2,
    float* __restrict__ dist_tab)
{
    __shared__ float pf[8][D];
    __shared__ float hid[8][D];
    int t = threadIdx.x;
    for (int i = t; i < 8 * D; i += 256) {
        int r = i >> 7, c = i & 127;
        float v;
        if (r < 6)      v = ple[r * D + c];
        else if (r == 6) v = vpe[c];
        else             v = sle[c];
        pf[r][c] = v;
    }
    __syncthreads();
    for (int i = t; i < 8 * D; i += 256) {
        int r = i >> 7, c = i & 127;
        float s = db1[c];
        for (int k = 0; k < D; ++k) s += pf[r][k] * dW1[k * D + c];
        hid[r][c] = gelu(s);
    }
    __syncthreads();
    if (t < 8 * H) {
        int r = t >> 2, h = t & 3;
        float s = db2[h];
        for (int k = 0; k < D; ++k) s += hid[r][k] * dW2[k * H + h];
        dist_tab[r * H + h] = s;
    }
}

// ---------------------------------------------------------------------------
// tab (MFMA): tab[i][n][:] = gelu(X[n]@tWin[i]+tbin[i]) @ tWout[i] + tbout[i]
// ---------------------------------------------------------------------------
__global__ __launch_bounds__(256) void k_tab_mfma(
    const float* __restrict__ X,
    const _Float16* __restrict__ Wt1,  // [PP][DT][128]  (tWin^T)
    const float* __restrict__ tbin,
    const _Float16* __restrict__ Wt2,  // [PP][DT][DT]   (tWout^T)
    const float* __restrict__ tbout,
    float* __restrict__ tab, int N)
{
    __shared__ _Float16 Ah[64][136];       // f16 X tile, stride 272B
    __shared__ _Float16 hidS[4][16][40];   // per-wave 16x32 stripe, stride 80B
    int t = threadIdx.x;
    int n0 = blockIdx.x * 64;
#pragma unroll
    for (int i = 0; i < 4; ++i) {
        int flat = t + i * 256;
        int r = flat >> 4, c = flat & 15;
        f16x8 v = f16x8_zero();
        if (n0 + r < N) {
            const float* xp = X + (size_t)(n0 + r) * D + c * 8;
            float4 x0 = *(const float4*)xp;
            float4 x1 = *(const float4*)(xp + 4);
            v[0] = (_Float16)x0.x; v[1] = (_Float16)x0.y;
            v[2] = (_Float16)x0.z; v[3] = (_Float16)x0.w;
            v[4] = (_Float16)x1.x; v[5] = (_Float16)x1.y;
            v[6] = (_Float16)x1.z; v[7] = (_Float16)x1.w;
        }
        *(f16x8*)&Ah[r][c * 8] = v;
    }
    __syncthreads();
    int w = t >> 6, lane = t & 63;
    int rt0 = w * 16, lr = lane & 15, lg = lane >> 4;
    f16x8 a1[4];
#pragma unroll
    for (int kk = 0; kk < 4; ++kk)
        a1[kk] = *(const f16x8*)&Ah[rt0 + lr][kk * 32 + lg * 8];

    for (int i = 0; i < PP; ++i) {
#pragma unroll
        for (int ct = 0; ct < 2; ++ct) {
            int col = ct * 16 + lr;
            f32x4 c1 = {0.f, 0.f, 0.f, 0.f};
#pragma unroll
            for (int kk = 0; kk < 4; ++kk) {
                f16x8 b = *(const f16x8*)&Wt1[((size_t)i * DT + col) * 128 + kk * 32 + lg * 8];
                c1 = __builtin_amdgcn_mfma_f32_16x16x32_f16(a1[kk], b, c1, 0, 0, 0);
            }
            float bb = tbin[i * DT + col];
#pragma unroll
            for (int j = 0; j < 4; ++j)
                hidS[w][lg * 4 + j][col] = (_Float16)gelu(c1[j] + bb);
        }
        f16x8 a2 = *(const f16x8*)&hidS[w][lr][lg * 8];
#pragma unroll
        for (int ct = 0; ct < 2; ++ct) {
            int col = ct * 16 + lr;
            f32x4 c2 = {0.f, 0.f, 0.f, 0.f};
            f16x8 b2 = *(const f16x8*)&Wt2[((size_t)i * DT + col) * DT + lg * 8];
            c2 = __builtin_amdgcn_mfma_f32_16x16x32_f16(a2, b2, c2, 0, 0, 0);
            float bb = tbout[i * DT + col];
#pragma unroll
            for (int j = 0; j < 4; ++j) {
                int row = n0 + rt0 + lg * 4 + j;
                if (row < N) tab[((size_t)i * N + row) * DT + col] = c2[j] + bb;
            }
        }
    }
}

// ---------------------------------------------------------------------------
// per-edge: path gather-mean -> small MLP -> + dist_tab lookup
// ---------------------------------------------------------------------------
__global__ __launch_bounds__(256) void k_edge_pre(
    const int* __restrict__ path, const int* __restrict__ vp, const int* __restrict__ sl,
    const float* __restrict__ tab, const float* __restrict__ dist_tab,
    const float* __restrict__ pW1, const float* __restrict__ pb1,
    const float* __restrict__ pW2, const float* __restrict__ pb2,
    float* __restrict__ base_attn, int E, int N)
{
    __shared__ float W1t[DT][DT];
    __shared__ float W2s[DT][H];
    __shared__ float b1s[DT];
    __shared__ float b2s[H];
    __shared__ float dts[8][H];
    int t = threadIdx.x;
    for (int i = t; i < DT * DT; i += 256) {
        int k = i >> 5, c = i & 31;
        W1t[c][k] = pW1[i];
    }
    if (t < DT * H) W2s[t >> 2][t & 3] = pW2[t];
    if (t < DT) b1s[t] = pb1[t];
    if (t < H)  b2s[t] = pb2[t];
    if (t < 32) dts[t >> 2][t & 3] = dist_tab[t];
    __syncthreads();
    int e = blockIdx.x * 256 + t;
    if (e >= E) return;
    int pl = 0;
    float acc[DT];
#pragma unroll
    for (int c = 0; c < DT; ++c) acc[c] = 0.0f;
#pragma unroll
    for (int i = 0; i < PP; ++i) {
        int p = path[(size_t)e * PP + i];
        if (p < -99) p = -1;
        if (p >= 0) {
            ++pl;
            const float* row = tab + ((size_t)i * N + p) * DT;
#pragma unroll
            for (int c4 = 0; c4 < 8; ++c4) {
                float4 v = *(const float4*)(row + c4 * 4);
                acc[c4 * 4 + 0] += v.x; acc[c4 * 4 + 1] += v.y;
                acc[c4 * 4 + 2] += v.z; acc[c4 * 4 + 3] += v.w;
            }
        }
    }
    float inv = 1.0f / (float)(pl > 0 ? pl : 1);
#pragma unroll
    for (int c = 0; c < DT; ++c) acc[c] *= inv;
    float o0 = b2s[0], o1 = b2s[1], o2 = b2s[2], o3 = b2s[3];
    for (int c = 0; c < DT; ++c) {
        float s = b1s[c];
#pragma unroll
        for (int k4 = 0; k4 < 8; ++k4) {
            float4 w = *(const float4*)&W1t[c][k4 * 4];
            s += acc[k4 * 4 + 0] * w.x + acc[k4 * 4 + 1] * w.y +
                 acc[k4 * 4 + 2] * w.z + acc[k4 * 4 + 3] * w.w;
        }
        float hv = gelu(s);
        o0 += hv * W2s[c][0]; o1 += hv * W2s[c][1];
        o2 += hv * W2s[c][2]; o3 += hv * W2s[c][3];
    }
    int se = (sl[e] == 1) ? 7 : ((vp[e] == 1) ? 6 : pl);
    float4 ov = make_float4(o0 + dts[se][0], o1 + dts[se][1],
                            o2 + dts[se][2], o3 + dts[se][3]);
    *(float4*)(base_attn + (size_t)e * 4) = ov;
}

// ---------------------------------------------------------------------------
// CSR build over dst
// ---------------------------------------------------------------------------
__global__ void k_count(const int* __restrict__ dst, int* __restrict__ deg, int E) {
    int e = blockIdx.x * 256 + threadIdx.x;
    if (e < E) atomicAdd(&deg[dst[e]], 1);
}

__global__ __launch_bounds__(1024) void k_scan(const int* __restrict__ deg,
                                               int* __restrict__ rowstart, int N) {
    __shared__ int sdata[1024];
    __shared__ int soff;
    int t = threadIdx.x;
    if (t == 0) soff = 0;
    for (int base = 0; base < N; base += 1024) {
        int v = (base + t < N) ? deg[base + t] : 0;
        __syncthreads();
        sdata[t] = v;
        __syncthreads();
        for (int off = 1; off < 1024; off <<= 1) {
            int x = (t >= off) ? sdata[t - off] : 0;
            __syncthreads();
            sdata[t] += x;
            __syncthreads();
        }
        int incl  = sdata[t];
        int total = sdata[1023];
        if (base + t < N) rowstart[base + t] = soff + incl - v;
        __syncthreads();
        if (t == 0) soff += total;
    }
    __syncthreads();
    if (t == 0) rowstart[N] = soff;
}

__global__ void k_scatter(const int* __restrict__ dst, const int* __restrict__ rowstart,
                          int* __restrict__ cursor, int* __restrict__ el, int E) {
    int e = blockIdx.x * 256 + threadIdx.x;
    if (e >= E) return;
    int d = dst[e];
    int pos = atomicAdd(&cursor[d], 1);
    el[rowstart[d] + pos] = e;
}

// ---------------------------------------------------------------------------
// LayerNorm: one wave per row of 128, writes f16 for MFMA consumers
// ---------------------------------------------------------------------------
__global__ __launch_bounds__(256) void k_ln(const float* __restrict__ X, const float* __restrict__ g,
                                            const float* __restrict__ b, _Float16* __restrict__ out, int N) {
    int gw   = (blockIdx.x * 256 + threadIdx.x) >> 6;
    int lane = threadIdx.x & 63;
    if (gw >= N) return;
    const float* x = X + (size_t)gw * D;
    float a0 = x[lane], a1 = x[lane + 64];
    float s = a0 + a1;
#pragma unroll
    for (int m = 1; m < 64; m <<= 1) s += __shfl_xor(s, m);
    float mu = s * (1.0f / 128.0f);
    float d0 = a0 - mu, d1 = a1 - mu;
    float v = d0 * d0 + d1 * d1;
#pragma unroll
    for (int m = 1; m < 64; m <<= 1) v += __shfl_xor(v, m);
    float r = rsqrtf(v * (1.0f / 128.0f) + 1e-5f);
    _Float16* o = out + (size_t)gw * D;
    o[lane]      = (_Float16)(d0 * r * g[lane]      + b[lane]);
    o[lane + 64] = (_Float16)(d1 * r * g[lane + 64] + b[lane + 64]);
}

// ---------------------------------------------------------------------------
// MFMA fragment conventions (gfx950 16x16x32, HW-verified layout):
//   A-frag: lane l holds A[m=l&15][k=(l>>4)*8 + 0..7]   (contig 16B)
//   B-frag: lane l holds B[k=(l>>4)*8+j][n=l&15] -> from Wt[n][k] contig 16B
//   C/D   : col = l&15, row = (l>>4)*4 + reg
// ---------------------------------------------------------------------------

// qkv GEMM: C16[N][384] = A[N][128] @ W[128][384] + bias (f16 out for gathers)
__global__ __launch_bounds__(256) void k_qkv_mfma(
    const _Float16* __restrict__ Hin, const _Float16* __restrict__ Wt, // [384][128]
    const float* __restrict__ bias, _Float16* __restrict__ C, int N)
{
    __shared__ _Float16 Ah[64][136];   // pad 8 f16: row stride 272B -> conflict-free frags
    int t = threadIdx.x;
    int n0 = blockIdx.x * 64;
#pragma unroll
    for (int i = 0; i < 4; ++i) {
        int flat = t + i * 256;
        int r = flat >> 4, c = flat & 15;
        f16x8 v = f16x8_zero();
        if (n0 + r < N) v = *(const f16x8*)&Hin[(size_t)(n0 + r) * D + c * 8];
        *(f16x8*)&Ah[r][c * 8] = v;
    }
    __syncthreads();
    int w = t >> 6, lane = t & 63;
    int rt0 = w * 16, lr = lane & 15, lg = lane >> 4;
    f16x8 a1[4];
#pragma unroll
    for (int kk = 0; kk < 4; ++kk)
        a1[kk] = *(const f16x8*)&Ah[rt0 + lr][kk * 32 + lg * 8];
#pragma unroll 4
    for (int ct = 0; ct < 24; ++ct) {
        int col = ct * 16 + lr;
        f32x4 acc = {0.f, 0.f, 0.f, 0.f};
#pragma unroll
        for (int kk = 0; kk < 4; ++kk) {
            f16x8 b = *(const f16x8*)&Wt[(size_t)col * 128 + kk * 32 + lg * 8];
            acc = __builtin_amdgcn_mfma_f32_16x16x32_f16(a1[kk], b, acc, 0, 0, 0);
        }
        float bb = bias[col];
#pragma unroll
        for (int i = 0; i < 4; ++i) {
            int row = n0 + rt0 + lg * 4 + i;
            if (row < N) C[(size_t)row * 384 + col] = (_Float16)(acc[i] + bb);
        }
    }
}

// res GEMM: Out = resid + Agg @ res_W + bias. block 64 rows, 4 waves
__global__ __launch_bounds__(256) void k_res_mfma(
    const _Float16* __restrict__ Agg, const _Float16* __restrict__ Wt, // [128][128]
    const float* __restrict__ bias, const float* __restrict__ resid,
    float* __restrict__ Out, int N)
{
    __shared__ _Float16 Ah[64][136];
    int t = threadIdx.x;
    int n0 = blockIdx.x * 64;
#pragma unroll
    for (int i = 0; i < 4; ++i) {
        int flat = t + i * 256;
        int r = flat >> 4, c = flat & 15;
        f16x8 v = f16x8_zero();
        if (n0 + r < N) v = *(const f16x8*)&Agg[(size_t)(n0 + r) * D + c * 8];
        *(f16x8*)&Ah[r][c * 8] = v;
    }
    __syncthreads();
    int w = t >> 6, lane = t & 63;
    int rt0 = w * 16, lr = lane & 15, lg = lane >> 4;
    f16x8 a1[4];
#pragma unroll
    for (int kk = 0; kk < 4; ++kk)
        a1[kk] = *(const f16x8*)&Ah[rt0 + lr][kk * 32 + lg * 8];
#pragma unroll
    for (int ct = 0; ct < 8; ++ct) {
        int col = ct * 16 + lr;
        f32x4 acc = {0.f, 0.f, 0.f, 0.f};
#pragma unroll
        for (int kk = 0; kk < 4; ++kk) {
            f16x8 b = *(const f16x8*)&Wt[(size_t)col * 128 + kk * 32 + lg * 8];
            acc = __builtin_amdgcn_mfma_f32_16x16x32_f16(a1[kk], b, acc, 0, 0, 0);
        }
        float bb = bias[col];
#pragma unroll
        for (int i = 0; i < 4; ++i) {
            int row = n0 + rt0 + lg * 4 + i;
            if (row < N) {
                size_t o = (size_t)row * D + col;
                Out[o] = resid[o] + acc[i] + bb;
            }
        }
    }
}

// fused FFN: Out = Xres + gelu(Hin@Win+bin)@Wout+bout. block 64 rows, 4 waves
__global__ __launch_bounds__(256) void k_ffn_mfma(
    const _Float16* __restrict__ Hin, const float* __restrict__ Xres,
    const _Float16* __restrict__ Wt1,  // [512][128] (Win^T)
    const float* __restrict__ bin,
    const _Float16* __restrict__ Wt2,  // [128][512] (Wout^T)
    const float* __restrict__ bout,
    float* __restrict__ Out, int N)
{
    __shared__ _Float16 Ah[64][136];
    __shared__ _Float16 hid[64][264];  // 256-col chunk + 8 pad (row stride 528B)
    int t = threadIdx.x;
    int n0 = blockIdx.x * 64;
#pragma unroll
    for (int i = 0; i < 4; ++i) {
        int flat = t + i * 256;
        int r = flat >> 4, c = flat & 15;
        f16x8 v = f16x8_zero();
        if (n0 + r < N) v = *(const f16x8*)&Hin[(size_t)(n0 + r) * D + c * 8];
        *(f16x8*)&Ah[r][c * 8] = v;
    }
    __syncthreads();
    int w = t >> 6, lane = t & 63;
    int rt0 = w * 16, lr = lane & 15, lg = lane >> 4;
    f16x8 a1[4];
#pragma unroll
    for (int kk = 0; kk < 4; ++kk)
        a1[kk] = *(const f16x8*)&Ah[rt0 + lr][kk * 32 + lg * 8];

    f32x4 acc2[8];
#pragma unroll
    for (int i = 0; i < 8; ++i) acc2[i] = (f32x4){0.f, 0.f, 0.f, 0.f};

    for (int ch = 0; ch < 2; ++ch) {
#pragma unroll 4
        for (int ct = 0; ct < 16; ++ct) {
            int hc = ch * 256 + ct * 16 + lr;
            f32x4 c1 = {0.f, 0.f, 0.f, 0.f};
#pragma unroll
            for (int kk = 0; kk < 4; ++kk) {
                f16x8 b = *(const f16x8*)&Wt1[(size_t)hc * 128 + kk * 32 + lg * 8];
                c1 = __builtin_amdgcn_mfma_f32_16x16x32_f16(a1[kk], b, c1, 0, 0, 0);
            }
            float bb = bin[hc];
#pragma unroll
            for (int i = 0; i < 4; ++i) {
                float v = gelu(c1[i] + bb);
                hid[rt0 + lg * 4 + i][ct * 16 + lr] = (_Float16)v;
            }
        }
#pragma unroll 2
        for (int kk2 = 0; kk2 < 8; ++kk2) {
            f16x8 a2 = *(const f16x8*)&hid[rt0 + lr][kk2 * 32 + lg * 8];
            int gk = ch * 256 + kk2 * 32 + lg * 8;
#pragma unroll
            for (int ct2 = 0; ct2 < 8; ++ct2) {
                f16x8 b2 = *(const f16x8*)&Wt2[(size_t)(ct2 * 16 + lr) * 512 + gk];
                acc2[ct2] = __builtin_amdgcn_mfma_f32_16x16x32_f16(a2, b2, acc2[ct2], 0, 0, 0);
            }
        }
    }
#pragma unroll
    for (int ct2 = 0; ct2 < 8; ++ct2) {
        int col = ct2 * 16 + lr;
        float bb = bout[col];
#pragma unroll
        for (int i = 0; i < 4; ++i) {
            int row = n0 + rt0 + lg * 4 + i;
            if (row < N) {
                size_t o = (size_t)row * D + col;
                Out[o] = Xres[o] + acc2[ct2][i] + bb;
            }
        }
    }
}

// ---------------------------------------------------------------------------
// fused attention: per node (wave), single pass over CSR edges.
// lane l owns dims {2l, 2l+1}; head = l>>4 (dh=32 -> 16 lanes per head).
// logit = (q[src].k[dst])*SCALE + base_attn -> ex; agg = (sum ex*v[src]) / sum ex
// ---------------------------------------------------------------------------
__global__ __launch_bounds__(256) void k_attn_agg(
    const _Float16* __restrict__ qkv,   // [N][384] f16: q|k|v
    const int* __restrict__ rowstart, const int* __restrict__ el,
    const int* __restrict__ src, const float* __restrict__ base_attn,
    _Float16* __restrict__ agg, int N)
{
    int gw   = (blockIdx.x * 256 + threadIdx.x) >> 6;
    int lane = threadIdx.x & 63;
    if (gw >= N) return;
    int head = lane >> 4;
    f16x2 kk = *(const f16x2*)&qkv[(size_t)gw * 384 + 128 + 2 * lane];
    float k0 = (float)kk[0], k1 = (float)kk[1];
    int beg = rowstart[gw], end = rowstart[gw + 1];
    float s = 0.0f, a0 = 0.0f, a1 = 0.0f;
    for (int i = beg; i < end; ++i) {
        int e  = el[i];
        int sr = src[e];
        const _Float16* row = qkv + (size_t)sr * 384;
        f16x2 qq = *(const f16x2*)&row[2 * lane];
        float t = (float)qq[0] * k0 + (float)qq[1] * k1;
#pragma unroll
        for (int m = 1; m <= 8; m <<= 1) t += __shfl_xor(t, m);
        float ex = expf(t * SCALE + base_attn[(size_t)e * 4 + head]);
        f16x2 vv = *(const f16x2*)&row[256 + 2 * lane];
        s  += ex;
        a0 += ex * (float)vv[0];
        a1 += ex * (float)vv[1];
    }
    float inv = (s > 0.0f) ? 1.0f / s : 0.0f;
    f16x2 o;
    o[0] = (_Float16)(a0 * inv);
    o[1] = (_Float16)(a1 * inv);
    *(f16x2*)&agg[(size_t)gw * D + 2 * lane] = o;
}

// ---------------------------------------------------------------------------
extern "C" void kernel_launch(void* const* d_in, const int* in_sizes, int n_in,
                              void* d_out, int out_size, void* d_ws, size_t ws_size,
                              hipStream_t stream) {
    const float* triplet_h = (const float*)d_in[0];
    const float* ple    = (const float*)d_in[1];
    const float* vpe    = (const float*)d_in[2];
    const float* sle    = (const float*)d_in[3];
    const float* dW1    = (const float*)d_in[4];
    const float* db1    = (const float*)d_in[5];
    const float* dW2    = (const float*)d_in[6];
    const float* db2    = (const float*)d_in[7];
    const float* tWin   = (const float*)d_in[8];
    const float* tbin   = (const float*)d_in[9];
    const float* tWout  = (const float*)d_in[10];
    const float* tbout  = (const float*)d_in[11];
    const float* pW1    = (const float*)d_in[12];
    const float* pb1    = (const float*)d_in[13];
    const float* pW2    = (const float*)d_in[14];
    const float* pb2    = (const float*)d_in[15];
    const float* ln1_g  = (const float*)d_in[16];
    const float* ln1_b  = (const float*)d_in[17];
    const float* qkv_W  = (const float*)d_in[18];
    const float* qkv_b  = (const float*)d_in[19];
    const float* rln_g  = (const float*)d_in[20];
    const float* rln_b  = (const float*)d_in[21];
    const float* res_W  = (const float*)d_in[22];
    const float* res_b  = (const float*)d_in[23];
    const float* fWin   = (const float*)d_in[24];
    const float* fbin   = (const float*)d_in[25];
    const float* fWout  = (const float*)d_in[26];
    const float* fbout  = (const float*)d_in[27];
    const int*   srcp   = (const int*)d_in[28];
    const int*   dstp   = (const int*)d_in[29];
    const int*   path   = (const int*)d_in[30];
    const int*   vp     = (const int*)d_in[31];
    const int*   sl     = (const int*)d_in[32];

    const int N = in_sizes[0] / D;
    const int E = in_sizes[28];

    char* ws = (char*)d_ws;
    size_t off = 0;
    auto alloc = [&](size_t bytes) -> void* {
        void* p = ws + off;
        off += (bytes + 255) & ~(size_t)255;
        return p;
    };
    float*     tab      = (float*)alloc((size_t)PP * N * DT * 4);
    float*     dist_tab = (float*)alloc(8 * H * 4);
    float*     base_attn= (float*)alloc((size_t)E * H * 4);
    int*       deg      = (int*)alloc((size_t)N * 4);
    int*       rowstart = (int*)alloc((size_t)(N + 1) * 4);
    int*       cursor   = (int*)alloc((size_t)N * 4);
    int*       el       = (int*)alloc((size_t)E * 4);
    _Float16*  hbuf     = (_Float16*)alloc((size_t)N * D * 2);
    _Float16*  qkvbuf   = (_Float16*)alloc((size_t)N * 384 * 2);
    _Float16*  aggbuf   = (_Float16*)alloc((size_t)N * D * 2);
    float*     bufA     = (float*)alloc((size_t)N * D * 4);
    float*     bufB     = (float*)alloc((size_t)N * D * 4);
    _Float16*  WtQ      = (_Float16*)alloc((size_t)NL * 384 * 128 * 2);
    _Float16*  WtR      = (_Float16*)alloc((size_t)NL * 128 * 128 * 2);
    _Float16*  Wt1      = (_Float16*)alloc((size_t)NL * 512 * 128 * 2);
    _Float16*  Wt2      = (_Float16*)alloc((size_t)NL * 128 * 512 * 2);
    _Float16*  WtTin    = (_Float16*)alloc((size_t)PP * DT * 128 * 2);
    _Float16*  WtTout   = (_Float16*)alloc((size_t)PP * DT * DT * 2);
    if (off > ws_size) return;

    hipMemsetAsync(deg,    0, (size_t)N * 4, stream);
    hipMemsetAsync(cursor, 0, (size_t)N * 4, stream);

    // weight transpose-convert (f32 [K][C] -> f16 [C][K])
    WPrep wp;
    wp.src[0] = qkv_W;                wp.dst[0] = WtQ;               wp.K[0] = 128; wp.C[0] = 384;
    wp.src[1] = qkv_W + 128 * 384;    wp.dst[1] = WtQ + 384 * 128;   wp.K[1] = 128; wp.C[1] = 384;
    wp.src[2] = res_W;                wp.dst[2] = WtR;               wp.K[2] = 128; wp.C[2] = 128;
    wp.src[3] = res_W + 128 * 128;    wp.dst[3] = WtR + 128 * 128;   wp.K[3] = 128; wp.C[3] = 128;
    wp.src[4] = fWin;                 wp.dst[4] = Wt1;               wp.K[4] = 128; wp.C[4] = 512;
    wp.src[5] = fWin + 128 * 512;     wp.dst[5] = Wt1 + 512 * 128;   wp.K[5] = 128; wp.C[5] = 512;
    wp.src[6] = fWout;                wp.dst[6] = Wt2;               wp.K[6] = 512; wp.C[6] = 128;
    wp.src[7] = fWout + 512 * 128;    wp.dst[7] = Wt2 + 128 * 512;   wp.K[7] = 512; wp.C[7] = 128;
    for (int i = 0; i < PP; ++i) {
        wp.src[8 + i]  = tWin  + (size_t)i * 128 * DT;
        wp.dst[8 + i]  = WtTin + (size_t)i * DT * 128;
        wp.K[8 + i] = 128; wp.C[8 + i] = DT;
        wp.src[13 + i] = tWout  + (size_t)i * DT * DT;
        wp.dst[13 + i] = WtTout + (size_t)i * DT * DT;
        wp.K[13 + i] = DT; wp.C[13 + i] = DT;
    }
    k_wprep<<<dim3(256, NWP), 256, 0, stream>>>(wp);

    k_dist_tab<<<1, 256, 0, stream>>>(ple, vpe, sle, dW1, db1, dW2, db2, dist_tab);
    k_tab_mfma<<<(N + 63) / 64, 256, 0, stream>>>(triplet_h, WtTin, tbin, WtTout, tbout, tab, N);
    k_edge_pre<<<(E + 255) / 256, 256, 0, stream>>>(path, vp, sl, tab, dist_tab,
                                                    pW1, pb1, pW2, pb2, base_attn, E, N);
    k_count<<<(E + 255) / 256, 256, 0, stream>>>(dstp, deg, E);
    k_scan<<<1, 1024, 0, stream>>>(deg, rowstart, N);
    k_scatter<<<(E + 255) / 256, 256, 0, stream>>>(dstp, rowstart, cursor, el, E);

    hipMemcpyAsync(bufA, triplet_h, (size_t)N * D * 4, hipMemcpyDeviceToDevice, stream);

    for (int l = 0; l < NL; ++l) {
        k_ln<<<(N + 3) / 4, 256, 0, stream>>>(bufA, ln1_g + l * D, ln1_b + l * D, hbuf, N);
        k_qkv_mfma<<<(N + 63) / 64, 256, 0, stream>>>(hbuf, WtQ + (size_t)l * 384 * 128,
                                                      qkv_b + l * 384, qkvbuf, N);
        k_attn_agg<<<(N + 3) / 4, 256, 0, stream>>>(qkvbuf, rowstart, el, srcp,
                                                    base_attn, aggbuf, N);
        k_res_mfma<<<(N + 63) / 64, 256, 0, stream>>>(aggbuf, WtR + (size_t)l * 128 * 128,
                                                      res_b + l * D, bufA, bufB, N);
        k_ln<<<(N + 3) / 4, 256, 0, stream>>>(bufB, rln_g + l * D, rln_b + l * D, hbuf, N);
        k_ffn_mfma<<<(N + 63) / 64, 256, 0, stream>>>(hbuf, bufB,
                                                      Wt1 + (size_t)l * 512 * 128, fbin + l * FF,
                                                      Wt2 + (size_t)l * 128 * 512, fbout + l * D,
                                                      bufA, N);
    }

    hipMemcpyAsync(d_out, bufA, (size_t)N * D * 4, hipMemcpyDeviceToDevice, stream);
}

// Round 13
// 710.042 us; speedup vs baseline: 2.2470x; 1.1080x over previous
//
#include <hip/hip_runtime.h>
#include <math.h>

#define D   128
#define H   4
#define PP  5
#define DT  32
#define FF  512
#define NL  2
#define SCALE 0.08838834764831845f

typedef _Float16 f16x8 __attribute__((ext_vector_type(8)));
typedef _Float16 f16x2 __attribute__((ext_vector_type(2)));
typedef float    f32x4 __attribute__((ext_vector_type(4)));

__device__ __forceinline__ float gelu(float x) {
    return 0.5f * x * (1.0f + erff(x * 0.7071067811865476f));
}

__device__ __forceinline__ f16x8 f16x8_zero() {
    f16x8 v;
#pragma unroll
    for (int j = 0; j < 8; ++j) v[j] = (_Float16)0.0f;
    return v;
}

// ---------------------------------------------------------------------------
// weight prep: transpose-convert f32 W[K][C] -> f16 Wt[C][K]  (18 matrices)
// grid MUST cover max K*C = 512*128 = 65536 -> 256 blocks x 256 threads.
// ---------------------------------------------------------------------------
#define NWP 18
struct WPrep {
    const float* src[NWP];
    _Float16*    dst[NWP];
    int K[NWP], C[NWP];
};

__global__ __launch_bounds__(256) void k_wprep(WPrep p) {
    int m = blockIdx.y;
    int n = blockIdx.x * 256 + threadIdx.x;
    int K = p.K[m], C = p.C[m];
    if (n >= K * C) return;
    int c = n / K, k = n - c * K;
    p.dst[m][n] = (_Float16)p.src[m][(size_t)k * C + c];
}

// ---------------------------------------------------------------------------
// dist_attn table: 8 possible pf vectors -> gelu(pf@dW1+db1)@dW2+db2  (8 x H)
// ---------------------------------------------------------------------------
__global__ __launch_bounds__(256) void k_dist_tab(
    const float* __restrict__ ple, const float* __restrict__ vpe, const float* __restrict__ sle,
    const float* __restrict__ dW1, const float* __restrict__ db1,
    const float* __restrict__ dW2, const float* __restrict__ db2,
    float* __restrict__ dist_tab)
{
    __shared__ float pf[8][D];
    __shared__ float hid[8][D];
    int t = threadIdx.x;
    for (int i = t; i < 8 * D; i += 256) {
        int r = i >> 7, c = i & 127;
        float v;
        if (r < 6)      v = ple[r * D + c];
        else if (r == 6) v = vpe[c];
        else             v = sle[c];
        pf[r][c] = v;
    }
    __syncthreads();
    for (int i = t; i < 8 * D; i += 256) {
        int r = i >> 7, c = i & 127;
        float s = db1[c];
        for (int k = 0; k < D; ++k) s += pf[r][k] * dW1[k * D + c];
        hid[r][c] = gelu(s);
    }
    __syncthreads();
    if (t < 8 * H) {
        int r = t >> 2, h = t & 3;
        float s = db2[h];
        for (int k = 0; k < D; ++k) s += hid[r][k] * dW2[k * H + h];
        dist_tab[r * H + h] = s;
    }
}

// ---------------------------------------------------------------------------
// tab (MFMA): tab[i][n][:] = gelu(X[n]@tWin[i]+tbin[i]) @ tWout[i] + tbout[i]
// ---------------------------------------------------------------------------
__global__ __launch_bounds__(256) void k_tab_mfma(
    const float* __restrict__ X,
    const _Float16* __restrict__ Wt1,  // [PP][DT][128]  (tWin^T)
    const float* __restrict__ tbin,
    const _Float16* __restrict__ Wt2,  // [PP][DT][DT]   (tWout^T)
    const float* __restrict__ tbout,
    float* __restrict__ tab, int N)
{
    __shared__ _Float16 Ah[64][136];       // f16 X tile, stride 272B
    __shared__ _Float16 hidS[4][16][40];   // per-wave 16x32 stripe, stride 80B
    int t = threadIdx.x;
    int n0 = blockIdx.x * 64;
#pragma unroll
    for (int i = 0; i < 4; ++i) {
        int flat = t + i * 256;
        int r = flat >> 4, c = flat & 15;
        f16x8 v = f16x8_zero();
        if (n0 + r < N) {
            const float* xp = X + (size_t)(n0 + r) * D + c * 8;
            float4 x0 = *(const float4*)xp;
            float4 x1 = *(const float4*)(xp + 4);
            v[0] = (_Float16)x0.x; v[1] = (_Float16)x0.y;
            v[2] = (_Float16)x0.z; v[3] = (_Float16)x0.w;
            v[4] = (_Float16)x1.x; v[5] = (_Float16)x1.y;
            v[6] = (_Float16)x1.z; v[7] = (_Float16)x1.w;
        }
        *(f16x8*)&Ah[r][c * 8] = v;
    }
    __syncthreads();
    int w = t >> 6, lane = t & 63;
    int rt0 = w * 16, lr = lane & 15, lg = lane >> 4;
    f16x8 a1[4];
#pragma unroll
    for (int kk = 0; kk < 4; ++kk)
        a1[kk] = *(const f16x8*)&Ah[rt0 + lr][kk * 32 + lg * 8];

    for (int i = 0; i < PP; ++i) {
#pragma unroll
        for (int ct = 0; ct < 2; ++ct) {
            int col = ct * 16 + lr;
            f32x4 c1 = {0.f, 0.f, 0.f, 0.f};
#pragma unroll
            for (int kk = 0; kk < 4; ++kk) {
                f16x8 b = *(const f16x8*)&Wt1[((size_t)i * DT + col) * 128 + kk * 32 + lg * 8];
                c1 = __builtin_amdgcn_mfma_f32_16x16x32_f16(a1[kk], b, c1, 0, 0, 0);
            }
            float bb = tbin[i * DT + col];
#pragma unroll
            for (int j = 0; j < 4; ++j)
                hidS[w][lg * 4 + j][col] = (_Float16)gelu(c1[j] + bb);
        }
        f16x8 a2 = *(const f16x8*)&hidS[w][lr][lg * 8];
#pragma unroll
        for (int ct = 0; ct < 2; ++ct) {
            int col = ct * 16 + lr;
            f32x4 c2 = {0.f, 0.f, 0.f, 0.f};
            f16x8 b2 = *(const f16x8*)&Wt2[((size_t)i * DT + col) * DT + lg * 8];
            c2 = __builtin_amdgcn_mfma_f32_16x16x32_f16(a2, b2, c2, 0, 0, 0);
            float bb = tbout[i * DT + col];
#pragma unroll
            for (int j = 0; j < 4; ++j) {
                int row = n0 + rt0 + lg * 4 + j;
                if (row < N) tab[((size_t)i * N + row) * DT + col] = c2[j] + bb;
            }
        }
    }
}

// ---------------------------------------------------------------------------
// per-edge: path gather-mean -> small MLP -> + dist_tab lookup
// ---------------------------------------------------------------------------
__global__ __launch_bounds__(256) void k_edge_pre(
    const int* __restrict__ path, const int* __restrict__ vp, const int* __restrict__ sl,
    const float* __restrict__ tab, const float* __restrict__ dist_tab,
    const float* __restrict__ pW1, const float* __restrict__ pb1,
    const float* __restrict__ pW2, const float* __restrict__ pb2,
    float* __restrict__ base_attn, int E, int N)
{
    __shared__ float W1t[DT][DT];
    __shared__ float W2s[DT][H];
    __shared__ float b1s[DT];
    __shared__ float b2s[H];
    __shared__ float dts[8][H];
    int t = threadIdx.x;
    for (int i = t; i < DT * DT; i += 256) {
        int k = i >> 5, c = i & 31;
        W1t[c][k] = pW1[i];
    }
    if (t < DT * H) W2s[t >> 2][t & 3] = pW2[t];
    if (t < DT) b1s[t] = pb1[t];
    if (t < H)  b2s[t] = pb2[t];
    if (t < 32) dts[t >> 2][t & 3] = dist_tab[t];
    __syncthreads();
    int e = blockIdx.x * 256 + t;
    if (e >= E) return;
    int pl = 0;
    float acc[DT];
#pragma unroll
    for (int c = 0; c < DT; ++c) acc[c] = 0.0f;
#pragma unroll
    for (int i = 0; i < PP; ++i) {
        int p = path[(size_t)e * PP + i];
        if (p < -99) p = -1;
        if (p >= 0) {
            ++pl;
            const float* row = tab + ((size_t)i * N + p) * DT;
#pragma unroll
            for (int c4 = 0; c4 < 8; ++c4) {
                float4 v = *(const float4*)(row + c4 * 4);
                acc[c4 * 4 + 0] += v.x; acc[c4 * 4 + 1] += v.y;
                acc[c4 * 4 + 2] += v.z; acc[c4 * 4 + 3] += v.w;
            }
        }
    }
    float inv = 1.0f / (float)(pl > 0 ? pl : 1);
#pragma unroll
    for (int c = 0; c < DT; ++c) acc[c] *= inv;
    float o0 = b2s[0], o1 = b2s[1], o2 = b2s[2], o3 = b2s[3];
    for (int c = 0; c < DT; ++c) {
        float s = b1s[c];
#pragma unroll
        for (int k4 = 0; k4 < 8; ++k4) {
            float4 w = *(const float4*)&W1t[c][k4 * 4];
            s += acc[k4 * 4 + 0] * w.x + acc[k4 * 4 + 1] * w.y +
                 acc[k4 * 4 + 2] * w.z + acc[k4 * 4 + 3] * w.w;
        }
        float hv = gelu(s);
        o0 += hv * W2s[c][0]; o1 += hv * W2s[c][1];
        o2 += hv * W2s[c][2]; o3 += hv * W2s[c][3];
    }
    int se = (sl[e] == 1) ? 7 : ((vp[e] == 1) ? 6 : pl);
    float4 ov = make_float4(o0 + dts[se][0], o1 + dts[se][1],
                            o2 + dts[se][2], o3 + dts[se][3]);
    *(float4*)(base_attn + (size_t)e * 4) = ov;
}

// ---------------------------------------------------------------------------
// CSR build over dst
// ---------------------------------------------------------------------------
__global__ void k_count(const int* __restrict__ dst, int* __restrict__ deg, int E) {
    int e = blockIdx.x * 256 + threadIdx.x;
    if (e < E) atomicAdd(&deg[dst[e]], 1);
}

__global__ __launch_bounds__(1024) void k_scan(const int* __restrict__ deg,
                                               int* __restrict__ rowstart, int N) {
    __shared__ int sdata[1024];
    __shared__ int soff;
    int t = threadIdx.x;
    if (t == 0) soff = 0;
    for (int base = 0; base < N; base += 1024) {
        int v = (base + t < N) ? deg[base + t] : 0;
        __syncthreads();
        sdata[t] = v;
        __syncthreads();
        for (int off = 1; off < 1024; off <<= 1) {
            int x = (t >= off) ? sdata[t - off] : 0;
            __syncthreads();
            sdata[t] += x;
            __syncthreads();
        }
        int incl  = sdata[t];
        int total = sdata[1023];
        if (base + t < N) rowstart[base + t] = soff + incl - v;
        __syncthreads();
        if (t == 0) soff += total;
    }
    __syncthreads();
    if (t == 0) rowstart[N] = soff;
}

__global__ void k_scatter(const int* __restrict__ dst, const int* __restrict__ rowstart,
                          int* __restrict__ cursor, int* __restrict__ el, int E) {
    int e = blockIdx.x * 256 + threadIdx.x;
    if (e >= E) return;
    int d = dst[e];
    int pos = atomicAdd(&cursor[d], 1);
    el[rowstart[d] + pos] = e;
}

// ---------------------------------------------------------------------------
// LayerNorm: one wave per row of 128, writes f16 for MFMA consumers
// ---------------------------------------------------------------------------
__global__ __launch_bounds__(256) void k_ln(const float* __restrict__ X, const float* __restrict__ g,
                                            const float* __restrict__ b, _Float16* __restrict__ out, int N) {
    int gw   = (blockIdx.x * 256 + threadIdx.x) >> 6;
    int lane = threadIdx.x & 63;
    if (gw >= N) return;
    const float* x = X + (size_t)gw * D;
    float a0 = x[lane], a1 = x[lane + 64];
    float s = a0 + a1;
#pragma unroll
    for (int m = 1; m < 64; m <<= 1) s += __shfl_xor(s, m);
    float mu = s * (1.0f / 128.0f);
    float d0 = a0 - mu, d1 = a1 - mu;
    float v = d0 * d0 + d1 * d1;
#pragma unroll
    for (int m = 1; m < 64; m <<= 1) v += __shfl_xor(v, m);
    float r = rsqrtf(v * (1.0f / 128.0f) + 1e-5f);
    _Float16* o = out + (size_t)gw * D;
    o[lane]      = (_Float16)(d0 * r * g[lane]      + b[lane]);
    o[lane + 64] = (_Float16)(d1 * r * g[lane + 64] + b[lane + 64]);
}

// ---------------------------------------------------------------------------
// MFMA fragment conventions (gfx950 16x16x32, HW-verified layout):
//   A-frag: lane l holds A[m=l&15][k=(l>>4)*8 + 0..7]   (contig 16B)
//   B-frag: lane l holds B[k=(l>>4)*8+j][n=l&15] -> from Wt[n][k] contig 16B
//   C/D   : col = l&15, row = (l>>4)*4 + reg
// ---------------------------------------------------------------------------

// qkv GEMM: C16[N][384] = A[N][128] @ W[128][384] + bias (f16 out for gathers)
__global__ __launch_bounds__(256) void k_qkv_mfma(
    const _Float16* __restrict__ Hin, const _Float16* __restrict__ Wt, // [384][128]
    const float* __restrict__ bias, _Float16* __restrict__ C, int N)
{
    __shared__ _Float16 Ah[64][136];   // pad 8 f16: row stride 272B -> conflict-free frags
    int t = threadIdx.x;
    int n0 = blockIdx.x * 64;
#pragma unroll
    for (int i = 0; i < 4; ++i) {
        int flat = t + i * 256;
        int r = flat >> 4, c = flat & 15;
        f16x8 v = f16x8_zero();
        if (n0 + r < N) v = *(const f16x8*)&Hin[(size_t)(n0 + r) * D + c * 8];
        *(f16x8*)&Ah[r][c * 8] = v;
    }
    __syncthreads();
    int w = t >> 6, lane = t & 63;
    int rt0 = w * 16, lr = lane & 15, lg = lane >> 4;
    f16x8 a1[4];
#pragma unroll
    for (int kk = 0; kk < 4; ++kk)
        a1[kk] = *(const f16x8*)&Ah[rt0 + lr][kk * 32 + lg * 8];
#pragma unroll 4
    for (int ct = 0; ct < 24; ++ct) {
        int col = ct * 16 + lr;
        f32x4 acc = {0.f, 0.f, 0.f, 0.f};
#pragma unroll
        for (int kk = 0; kk < 4; ++kk) {
            f16x8 b = *(const f16x8*)&Wt[(size_t)col * 128 + kk * 32 + lg * 8];
            acc = __builtin_amdgcn_mfma_f32_16x16x32_f16(a1[kk], b, acc, 0, 0, 0);
        }
        float bb = bias[col];
#pragma unroll
        for (int i = 0; i < 4; ++i) {
            int row = n0 + rt0 + lg * 4 + i;
            if (row < N) C[(size_t)row * 384 + col] = (_Float16)(acc[i] + bb);
        }
    }
}

// res GEMM: Out = resid + Agg @ res_W + bias. block 64 rows, 4 waves
__global__ __launch_bounds__(256) void k_res_mfma(
    const _Float16* __restrict__ Agg, const _Float16* __restrict__ Wt, // [128][128]
    const float* __restrict__ bias, const float* __restrict__ resid,
    float* __restrict__ Out, int N)
{
    __shared__ _Float16 Ah[64][136];
    int t = threadIdx.x;
    int n0 = blockIdx.x * 64;
#pragma unroll
    for (int i = 0; i < 4; ++i) {
        int flat = t + i * 256;
        int r = flat >> 4, c = flat & 15;
        f16x8 v = f16x8_zero();
        if (n0 + r < N) v = *(const f16x8*)&Agg[(size_t)(n0 + r) * D + c * 8];
        *(f16x8*)&Ah[r][c * 8] = v;
    }
    __syncthreads();
    int w = t >> 6, lane = t & 63;
    int rt0 = w * 16, lr = lane & 15, lg = lane >> 4;
    f16x8 a1[4];
#pragma unroll
    for (int kk = 0; kk < 4; ++kk)
        a1[kk] = *(const f16x8*)&Ah[rt0 + lr][kk * 32 + lg * 8];
#pragma unroll
    for (int ct = 0; ct < 8; ++ct) {
        int col = ct * 16 + lr;
        f32x4 acc = {0.f, 0.f, 0.f, 0.f};
#pragma unroll
        for (int kk = 0; kk < 4; ++kk) {
            f16x8 b = *(const f16x8*)&Wt[(size_t)col * 128 + kk * 32 + lg * 8];
            acc = __builtin_amdgcn_mfma_f32_16x16x32_f16(a1[kk], b, acc, 0, 0, 0);
        }
        float bb = bias[col];
#pragma unroll
        for (int i = 0; i < 4; ++i) {
            int row = n0 + rt0 + lg * 4 + i;
            if (row < N) {
                size_t o = (size_t)row * D + col;
                Out[o] = resid[o] + acc[i] + bb;
            }
        }
    }
}

// fused FFN: Out = Xres + gelu(Hin@Win+bin)@Wout+bout. block 64 rows, 4 waves
__global__ __launch_bounds__(256) void k_ffn_mfma(
    const _Float16* __restrict__ Hin, const float* __restrict__ Xres,
    const _Float16* __restrict__ Wt1,  // [512][128] (Win^T)
    const float* __restrict__ bin,
    const _Float16* __restrict__ Wt2,  // [128][512] (Wout^T)
    const float* __restrict__ bout,
    float* __restrict__ Out, int N)
{
    __shared__ _Float16 Ah[64][136];
    __shared__ _Float16 hid[64][264];  // 256-col chunk + 8 pad (row stride 528B)
    int t = threadIdx.x;
    int n0 = blockIdx.x * 64;
#pragma unroll
    for (int i = 0; i < 4; ++i) {
        int flat = t + i * 256;
        int r = flat >> 4, c = flat & 15;
        f16x8 v = f16x8_zero();
        if (n0 + r < N) v = *(const f16x8*)&Hin[(size_t)(n0 + r) * D + c * 8];
        *(f16x8*)&Ah[r][c * 8] = v;
    }
    __syncthreads();
    int w = t >> 6, lane = t & 63;
    int rt0 = w * 16, lr = lane & 15, lg = lane >> 4;
    f16x8 a1[4];
#pragma unroll
    for (int kk = 0; kk < 4; ++kk)
        a1[kk] = *(const f16x8*)&Ah[rt0 + lr][kk * 32 + lg * 8];

    f32x4 acc2[8];
#pragma unroll
    for (int i = 0; i < 8; ++i) acc2[i] = (f32x4){0.f, 0.f, 0.f, 0.f};

    for (int ch = 0; ch < 2; ++ch) {
#pragma unroll 4
        for (int ct = 0; ct < 16; ++ct) {
            int hc = ch * 256 + ct * 16 + lr;
            f32x4 c1 = {0.f, 0.f, 0.f, 0.f};
#pragma unroll
            for (int kk = 0; kk < 4; ++kk) {
                f16x8 b = *(const f16x8*)&Wt1[(size_t)hc * 128 + kk * 32 + lg * 8];
                c1 = __builtin_amdgcn_mfma_f32_16x16x32_f16(a1[kk], b, c1, 0, 0, 0);
            }
            float bb = bin[hc];
#pragma unroll
            for (int i = 0; i < 4; ++i) {
                float v = gelu(c1[i] + bb);
                hid[rt0 + lg * 4 + i][ct * 16 + lr] = (_Float16)v;
            }
        }
#pragma unroll 2
        for (int kk2 = 0; kk2 < 8; ++kk2) {
            f16x8 a2 = *(const f16x8*)&hid[rt0 + lr][kk2 * 32 + lg * 8];
            int gk = ch * 256 + kk2 * 32 + lg * 8;
#pragma unroll
            for (int ct2 = 0; ct2 < 8; ++ct2) {
                f16x8 b2 = *(const f16x8*)&Wt2[(size_t)(ct2 * 16 + lr) * 512 + gk];
                acc2[ct2] = __builtin_amdgcn_mfma_f32_16x16x32_f16(a2, b2, acc2[ct2], 0, 0, 0);
            }
        }
    }
#pragma unroll
    for (int ct2 = 0; ct2 < 8; ++ct2) {
        int col = ct2 * 16 + lr;
        float bb = bout[col];
#pragma unroll
        for (int i = 0; i < 4; ++i) {
            int row = n0 + rt0 + lg * 4 + i;
            if (row < N) {
                size_t o = (size_t)row * D + col;
                Out[o] = Xres[o] + acc2[ct2][i] + bb;
            }
        }
    }
}

// ---------------------------------------------------------------------------
// fused attention: per node (wave), single pass over CSR edges.
// lane l owns dims {2l, 2l+1}; head = l>>4 (dh=32 -> 16 lanes per head).
// 4-way edge unroll: 4 independent gather chains in flight (latency-bound fix).
// ---------------------------------------------------------------------------
__global__ __launch_bounds__(256) void k_attn_agg(
    const _Float16* __restrict__ qkv,   // [N][384] f16: q|k|v
    const int* __restrict__ rowstart, const int* __restrict__ el,
    const int* __restrict__ src, const float* __restrict__ base_attn,
    _Float16* __restrict__ agg, int N)
{
    int gw   = (blockIdx.x * 256 + threadIdx.x) >> 6;
    int lane = threadIdx.x & 63;
    if (gw >= N) return;
    int head = lane >> 4;
    f16x2 kk = *(const f16x2*)&qkv[(size_t)gw * 384 + 128 + 2 * lane];
    float k0 = (float)kk[0], k1 = (float)kk[1];
    int beg = rowstart[gw], end = rowstart[gw + 1];
    float s = 0.0f, a0 = 0.0f, a1 = 0.0f;
    int i = beg;
    for (; i + 4 <= end; i += 4) {
        int   e[4], sr[4];
        f16x2 qq[4], vv[4];
        float bb[4], tt[4];
#pragma unroll
        for (int j = 0; j < 4; ++j) e[j] = el[i + j];
#pragma unroll
        for (int j = 0; j < 4; ++j) sr[j] = src[e[j]];
#pragma unroll
        for (int j = 0; j < 4; ++j) {
            const _Float16* row = qkv + (size_t)sr[j] * 384;
            qq[j] = *(const f16x2*)&row[2 * lane];
            vv[j] = *(const f16x2*)&row[256 + 2 * lane];
            bb[j] = base_attn[(size_t)e[j] * 4 + head];
        }
#pragma unroll
        for (int j = 0; j < 4; ++j)
            tt[j] = (float)qq[j][0] * k0 + (float)qq[j][1] * k1;
#pragma unroll
        for (int m = 1; m <= 8; m <<= 1) {
#pragma unroll
            for (int j = 0; j < 4; ++j) tt[j] += __shfl_xor(tt[j], m);
        }
#pragma unroll
        for (int j = 0; j < 4; ++j) {
            float ex = expf(tt[j] * SCALE + bb[j]);
            s  += ex;
            a0 += ex * (float)vv[j][0];
            a1 += ex * (float)vv[j][1];
        }
    }
    for (; i < end; ++i) {
        int e  = el[i];
        int sr = src[e];
        const _Float16* row = qkv + (size_t)sr * 384;
        f16x2 qq = *(const f16x2*)&row[2 * lane];
        float t = (float)qq[0] * k0 + (float)qq[1] * k1;
#pragma unroll
        for (int m = 1; m <= 8; m <<= 1) t += __shfl_xor(t, m);
        float ex = expf(t * SCALE + base_attn[(size_t)e * 4 + head]);
        f16x2 vv = *(const f16x2*)&row[256 + 2 * lane];
        s  += ex;
        a0 += ex * (float)vv[0];
        a1 += ex * (float)vv[1];
    }
    float inv = (s > 0.0f) ? 1.0f / s : 0.0f;
    f16x2 o;
    o[0] = (_Float16)(a0 * inv);
    o[1] = (_Float16)(a1 * inv);
    *(f16x2*)&agg[(size_t)gw * D + 2 * lane] = o;
}

// ---------------------------------------------------------------------------
extern "C" void kernel_launch(void* const* d_in, const int* in_sizes, int n_in,
                              void* d_out, int out_size, void* d_ws, size_t ws_size,
                              hipStream_t stream) {
    const float* triplet_h = (const float*)d_in[0];
    const float* ple    = (const float*)d_in[1];
    const float* vpe    = (const float*)d_in[2];
    const float* sle    = (const float*)d_in[3];
    const float* dW1    = (const float*)d_in[4];
    const float* db1    = (const float*)d_in[5];
    const float* dW2    = (const float*)d_in[6];
    const float* db2    = (const float*)d_in[7];
    const float* tWin   = (const float*)d_in[8];
    const float* tbin   = (const float*)d_in[9];
    const float* tWout  = (const float*)d_in[10];
    const float* tbout  = (const float*)d_in[11];
    const float* pW1    = (const float*)d_in[12];
    const float* pb1    = (const float*)d_in[13];
    const float* pW2    = (const float*)d_in[14];
    const float* pb2    = (const float*)d_in[15];
    const float* ln1_g  = (const float*)d_in[16];
    const float* ln1_b  = (const float*)d_in[17];
    const float* qkv_W  = (const float*)d_in[18];
    const float* qkv_b  = (const float*)d_in[19];
    const float* rln_g  = (const float*)d_in[20];
    const float* rln_b  = (const float*)d_in[21];
    const float* res_W  = (const float*)d_in[22];
    const float* res_b  = (const float*)d_in[23];
    const float* fWin   = (const float*)d_in[24];
    const float* fbin   = (const float*)d_in[25];
    const float* fWout  = (const float*)d_in[26];
    const float* fbout  = (const float*)d_in[27];
    const int*   srcp   = (const int*)d_in[28];
    const int*   dstp   = (const int*)d_in[29];
    const int*   path   = (const int*)d_in[30];
    const int*   vp     = (const int*)d_in[31];
    const int*   sl     = (const int*)d_in[32];

    const int N = in_sizes[0] / D;
    const int E = in_sizes[28];

    char* ws = (char*)d_ws;
    size_t off = 0;
    auto alloc = [&](size_t bytes) -> void* {
        void* p = ws + off;
        off += (bytes + 255) & ~(size_t)255;
        return p;
    };
    float*     tab      = (float*)alloc((size_t)PP * N * DT * 4);
    float*     dist_tab = (float*)alloc(8 * H * 4);
    float*     base_attn= (float*)alloc((size_t)E * H * 4);
    int*       deg      = (int*)alloc((size_t)N * 4);
    int*       rowstart = (int*)alloc((size_t)(N + 1) * 4);
    int*       cursor   = (int*)alloc((size_t)N * 4);
    int*       el       = (int*)alloc((size_t)E * 4);
    _Float16*  hbuf     = (_Float16*)alloc((size_t)N * D * 2);
    _Float16*  qkvbuf   = (_Float16*)alloc((size_t)N * 384 * 2);
    _Float16*  aggbuf   = (_Float16*)alloc((size_t)N * D * 2);
    float*     bufA     = (float*)alloc((size_t)N * D * 4);
    float*     bufB     = (float*)alloc((size_t)N * D * 4);
    _Float16*  WtQ      = (_Float16*)alloc((size_t)NL * 384 * 128 * 2);
    _Float16*  WtR      = (_Float16*)alloc((size_t)NL * 128 * 128 * 2);
    _Float16*  Wt1      = (_Float16*)alloc((size_t)NL * 512 * 128 * 2);
    _Float16*  Wt2      = (_Float16*)alloc((size_t)NL * 128 * 512 * 2);
    _Float16*  WtTin    = (_Float16*)alloc((size_t)PP * DT * 128 * 2);
    _Float16*  WtTout   = (_Float16*)alloc((size_t)PP * DT * DT * 2);
    if (off > ws_size) return;

    hipMemsetAsync(deg,    0, (size_t)N * 4, stream);
    hipMemsetAsync(cursor, 0, (size_t)N * 4, stream);

    // weight transpose-convert (f32 [K][C] -> f16 [C][K])
    WPrep wp;
    wp.src[0] = qkv_W;                wp.dst[0] = WtQ;               wp.K[0] = 128; wp.C[0] = 384;
    wp.src[1] = qkv_W + 128 * 384;    wp.dst[1] = WtQ + 384 * 128;   wp.K[1] = 128; wp.C[1] = 384;
    wp.src[2] = res_W;                wp.dst[2] = WtR;               wp.K[2] = 128; wp.C[2] = 128;
    wp.src[3] = res_W + 128 * 128;    wp.dst[3] = WtR + 128 * 128;   wp.K[3] = 128; wp.C[3] = 128;
    wp.src[4] = fWin;                 wp.dst[4] = Wt1;               wp.K[4] = 128; wp.C[4] = 512;
    wp.src[5] = fWin + 128 * 512;     wp.dst[5] = Wt1 + 512 * 128;   wp.K[5] = 128; wp.C[5] = 512;
    wp.src[6] = fWout;                wp.dst[6] = Wt2;               wp.K[6] = 512; wp.C[6] = 128;
    wp.src[7] = fWout + 512 * 128;    wp.dst[7] = Wt2 + 128 * 512;   wp.K[7] = 512; wp.C[7] = 128;
    for (int i = 0; i < PP; ++i) {
        wp.src[8 + i]  = tWin  + (size_t)i * 128 * DT;
        wp.dst[8 + i]  = WtTin + (size_t)i * DT * 128;
        wp.K[8 + i] = 128; wp.C[8 + i] = DT;
        wp.src[13 + i] = tWout  + (size_t)i * DT * DT;
        wp.dst[13 + i] = WtTout + (size_t)i * DT * DT;
        wp.K[13 + i] = DT; wp.C[13 + i] = DT;
    }
    k_wprep<<<dim3(256, NWP), 256, 0, stream>>>(wp);

    k_dist_tab<<<1, 256, 0, stream>>>(ple, vpe, sle, dW1, db1, dW2, db2, dist_tab);
    k_tab_mfma<<<(N + 63) / 64, 256, 0, stream>>>(triplet_h, WtTin, tbin, WtTout, tbout, tab, N);
    k_edge_pre<<<(E + 255) / 256, 256, 0, stream>>>(path, vp, sl, tab, dist_tab,
                                                    pW1, pb1, pW2, pb2, base_attn, E, N);
    k_count<<<(E + 255) / 256, 256, 0, stream>>>(dstp, deg, E);
    k_scan<<<1, 1024, 0, stream>>>(deg, rowstart, N);
    k_scatter<<<(E + 255) / 256, 256, 0, stream>>>(dstp, rowstart, cursor, el, E);

    hipMemcpyAsync(bufA, triplet_h, (size_t)N * D * 4, hipMemcpyDeviceToDevice, stream);

    for (int l = 0; l < NL; ++l) {
        k_ln<<<(N + 3) / 4, 256, 0, stream>>>(bufA, ln1_g + l * D, ln1_b + l * D, hbuf, N);
        k_qkv_mfma<<<(N + 63) / 64, 256, 0, stream>>>(hbuf, WtQ + (size_t)l * 384 * 128,
                                                      qkv_b + l * 384, qkvbuf, N);
        k_attn_agg<<<(N + 3) / 4, 256, 0, stream>>>(qkvbuf, rowstart, el, srcp,
                                                    base_attn, aggbuf, N);
        k_res_mfma<<<(N + 63) / 64, 256, 0, stream>>>(aggbuf, WtR + (size_t)l * 128 * 128,
                                                      res_b + l * D, bufA, bufB, N);
        k_ln<<<(N + 3) / 4, 256, 0, stream>>>(bufB, rln_g + l * D, rln_b + l * D, hbuf, N);
        k_ffn_mfma<<<(N + 63) / 64, 256, 0, stream>>>(hbuf, bufB,
                                                      Wt1 + (size_t)l * 512 * 128, fbin + l * FF,
                                                      Wt2 + (size_t)l * 128 * 512, fbout + l * D,
                                                      bufA, N);
    }

    hipMemcpyAsync(d_out, bufA, (size_t)N * D * 4, hipMemcpyDeviceToDevice, stream);
}

// Round 14
// 615.014 us; speedup vs baseline: 2.5941x; 1.1545x over previous
//
#include <hip/hip_runtime.h>
#include <math.h>

#define D   128
#define H   4
#define PP  5
#define DT  32
#define FF  512
#define NL  2
#define SCALE 0.08838834764831845f

typedef _Float16 f16x8 __attribute__((ext_vector_type(8)));
typedef _Float16 f16x2 __attribute__((ext_vector_type(2)));
typedef float    f32x4 __attribute__((ext_vector_type(4)));

__device__ __forceinline__ float gelu(float x) {
    return 0.5f * x * (1.0f + erff(x * 0.7071067811865476f));
}

__device__ __forceinline__ f16x8 f16x8_zero() {
    f16x8 v;
#pragma unroll
    for (int j = 0; j < 8; ++j) v[j] = (_Float16)0.0f;
    return v;
}

// ---------------------------------------------------------------------------
// weight prep: transpose-convert f32 W[K][C] -> f16 Wt[C][K]  (18 matrices)
// grid MUST cover max K*C = 512*128 = 65536 -> 256 blocks x 256 threads.
// ---------------------------------------------------------------------------
#define NWP 18
struct WPrep {
    const float* src[NWP];
    _Float16*    dst[NWP];
    int K[NWP], C[NWP];
};

__global__ __launch_bounds__(256) void k_wprep(WPrep p) {
    int m = blockIdx.y;
    int n = blockIdx.x * 256 + threadIdx.x;
    int K = p.K[m], C = p.C[m];
    if (n >= K * C) return;
    int c = n / K, k = n - c * K;
    p.dst[m][n] = (_Float16)p.src[m][(size_t)k * C + c];
}

// ---------------------------------------------------------------------------
// dist_attn table: 8 possible pf vectors -> gelu(pf@dW1+db1)@dW2+db2  (8 x H)
// ---------------------------------------------------------------------------
__global__ __launch_bounds__(256) void k_dist_tab(
    const float* __restrict__ ple, const float* __restrict__ vpe, const float* __restrict__ sle,
    const float* __restrict__ dW1, const float* __restrict__ db1,
    const float* __restrict__ dW2, const float* __restrict__ db2,
    float* __restrict__ dist_tab)
{
    __shared__ float pf[8][D];
    __shared__ float hid[8][D];
    int t = threadIdx.x;
    for (int i = t; i < 8 * D; i += 256) {
        int r = i >> 7, c = i & 127;
        float v;
        if (r < 6)      v = ple[r * D + c];
        else if (r == 6) v = vpe[c];
        else             v = sle[c];
        pf[r][c] = v;
    }
    __syncthreads();
    for (int i = t; i < 8 * D; i += 256) {
        int r = i >> 7, c = i & 127;
        float s = db1[c];
        for (int k = 0; k < D; ++k) s += pf[r][k] * dW1[k * D + c];
        hid[r][c] = gelu(s);
    }
    __syncthreads();
    if (t < 8 * H) {
        int r = t >> 2, h = t & 3;
        float s = db2[h];
        for (int k = 0; k < D; ++k) s += hid[r][k] * dW2[k * H + h];
        dist_tab[r * H + h] = s;
    }
}

// ---------------------------------------------------------------------------
// tab (MFMA): tab[i][n][:] = gelu(X[n]@tWin[i]+tbin[i]) @ tWout[i] + tbout[i]
// ---------------------------------------------------------------------------
__global__ __launch_bounds__(256) void k_tab_mfma(
    const float* __restrict__ X,
    const _Float16* __restrict__ Wt1,  // [PP][DT][128]  (tWin^T)
    const float* __restrict__ tbin,
    const _Float16* __restrict__ Wt2,  // [PP][DT][DT]   (tWout^T)
    const float* __restrict__ tbout,
    float* __restrict__ tab, int N)
{
    __shared__ _Float16 Ah[64][136];       // f16 X tile, stride 272B
    __shared__ _Float16 hidS[4][16][40];   // per-wave 16x32 stripe, stride 80B
    int t = threadIdx.x;
    int n0 = blockIdx.x * 64;
#pragma unroll
    for (int i = 0; i < 4; ++i) {
        int flat = t + i * 256;
        int r = flat >> 4, c = flat & 15;
        f16x8 v = f16x8_zero();
        if (n0 + r < N) {
            const float* xp = X + (size_t)(n0 + r) * D + c * 8;
            float4 x0 = *(const float4*)xp;
            float4 x1 = *(const float4*)(xp + 4);
            v[0] = (_Float16)x0.x; v[1] = (_Float16)x0.y;
            v[2] = (_Float16)x0.z; v[3] = (_Float16)x0.w;
            v[4] = (_Float16)x1.x; v[5] = (_Float16)x1.y;
            v[6] = (_Float16)x1.z; v[7] = (_Float16)x1.w;
        }
        *(f16x8*)&Ah[r][c * 8] = v;
    }
    __syncthreads();
    int w = t >> 6, lane = t & 63;
    int rt0 = w * 16, lr = lane & 15, lg = lane >> 4;
    f16x8 a1[4];
#pragma unroll
    for (int kk = 0; kk < 4; ++kk)
        a1[kk] = *(const f16x8*)&Ah[rt0 + lr][kk * 32 + lg * 8];

    for (int i = 0; i < PP; ++i) {
#pragma unroll
        for (int ct = 0; ct < 2; ++ct) {
            int col = ct * 16 + lr;
            f32x4 c1 = {0.f, 0.f, 0.f, 0.f};
#pragma unroll
            for (int kk = 0; kk < 4; ++kk) {
                f16x8 b = *(const f16x8*)&Wt1[((size_t)i * DT + col) * 128 + kk * 32 + lg * 8];
                c1 = __builtin_amdgcn_mfma_f32_16x16x32_f16(a1[kk], b, c1, 0, 0, 0);
            }
            float bb = tbin[i * DT + col];
#pragma unroll
            for (int j = 0; j < 4; ++j)
                hidS[w][lg * 4 + j][col] = (_Float16)gelu(c1[j] + bb);
        }
        f16x8 a2 = *(const f16x8*)&hidS[w][lr][lg * 8];
#pragma unroll
        for (int ct = 0; ct < 2; ++ct) {
            int col = ct * 16 + lr;
            f32x4 c2 = {0.f, 0.f, 0.f, 0.f};
            f16x8 b2 = *(const f16x8*)&Wt2[((size_t)i * DT + col) * DT + lg * 8];
            c2 = __builtin_amdgcn_mfma_f32_16x16x32_f16(a2, b2, c2, 0, 0, 0);
            float bb = tbout[i * DT + col];
#pragma unroll
            for (int j = 0; j < 4; ++j) {
                int row = n0 + rt0 + lg * 4 + j;
                if (row < N) tab[((size_t)i * N + row) * DT + col] = c2[j] + bb;
            }
        }
    }
}

// ---------------------------------------------------------------------------
// per-edge: path gather-mean -> small MLP -> + dist_tab lookup
// ---------------------------------------------------------------------------
__global__ __launch_bounds__(256) void k_edge_pre(
    const int* __restrict__ path, const int* __restrict__ vp, const int* __restrict__ sl,
    const float* __restrict__ tab, const float* __restrict__ dist_tab,
    const float* __restrict__ pW1, const float* __restrict__ pb1,
    const float* __restrict__ pW2, const float* __restrict__ pb2,
    float* __restrict__ base_attn, int E, int N)
{
    __shared__ float W1t[DT][DT];
    __shared__ float W2s[DT][H];
    __shared__ float b1s[DT];
    __shared__ float b2s[H];
    __shared__ float dts[8][H];
    int t = threadIdx.x;
    for (int i = t; i < DT * DT; i += 256) {
        int k = i >> 5, c = i & 31;
        W1t[c][k] = pW1[i];
    }
    if (t < DT * H) W2s[t >> 2][t & 3] = pW2[t];
    if (t < DT) b1s[t] = pb1[t];
    if (t < H)  b2s[t] = pb2[t];
    if (t < 32) dts[t >> 2][t & 3] = dist_tab[t];
    __syncthreads();
    int e = blockIdx.x * 256 + t;
    if (e >= E) return;
    int pl = 0;
    float acc[DT];
#pragma unroll
    for (int c = 0; c < DT; ++c) acc[c] = 0.0f;
#pragma unroll
    for (int i = 0; i < PP; ++i) {
        int p = path[(size_t)e * PP + i];
        if (p < -99) p = -1;
        if (p >= 0) {
            ++pl;
            const float* row = tab + ((size_t)i * N + p) * DT;
#pragma unroll
            for (int c4 = 0; c4 < 8; ++c4) {
                float4 v = *(const float4*)(row + c4 * 4);
                acc[c4 * 4 + 0] += v.x; acc[c4 * 4 + 1] += v.y;
                acc[c4 * 4 + 2] += v.z; acc[c4 * 4 + 3] += v.w;
            }
        }
    }
    float inv = 1.0f / (float)(pl > 0 ? pl : 1);
#pragma unroll
    for (int c = 0; c < DT; ++c) acc[c] *= inv;
    float o0 = b2s[0], o1 = b2s[1], o2 = b2s[2], o3 = b2s[3];
    for (int c = 0; c < DT; ++c) {
        float s = b1s[c];
#pragma unroll
        for (int k4 = 0; k4 < 8; ++k4) {
            float4 w = *(const float4*)&W1t[c][k4 * 4];
            s += acc[k4 * 4 + 0] * w.x + acc[k4 * 4 + 1] * w.y +
                 acc[k4 * 4 + 2] * w.z + acc[k4 * 4 + 3] * w.w;
        }
        float hv = gelu(s);
        o0 += hv * W2s[c][0]; o1 += hv * W2s[c][1];
        o2 += hv * W2s[c][2]; o3 += hv * W2s[c][3];
    }
    int se = (sl[e] == 1) ? 7 : ((vp[e] == 1) ? 6 : pl);
    float4 ov = make_float4(o0 + dts[se][0], o1 + dts[se][1],
                            o2 + dts[se][2], o3 + dts[se][3]);
    *(float4*)(base_attn + (size_t)e * 4) = ov;
}

// ---------------------------------------------------------------------------
// CSR build over dst
// ---------------------------------------------------------------------------
__global__ void k_count(const int* __restrict__ dst, int* __restrict__ deg, int E) {
    int e = blockIdx.x * 256 + threadIdx.x;
    if (e < E) atomicAdd(&deg[dst[e]], 1);
}

__global__ __launch_bounds__(1024) void k_scan(const int* __restrict__ deg,
                                               int* __restrict__ rowstart, int N) {
    __shared__ int sdata[1024];
    __shared__ int soff;
    int t = threadIdx.x;
    if (t == 0) soff = 0;
    for (int base = 0; base < N; base += 1024) {
        int v = (base + t < N) ? deg[base + t] : 0;
        __syncthreads();
        sdata[t] = v;
        __syncthreads();
        for (int off = 1; off < 1024; off <<= 1) {
            int x = (t >= off) ? sdata[t - off] : 0;
            __syncthreads();
            sdata[t] += x;
            __syncthreads();
        }
        int incl  = sdata[t];
        int total = sdata[1023];
        if (base + t < N) rowstart[base + t] = soff + incl - v;
        __syncthreads();
        if (t == 0) soff += total;
    }
    __syncthreads();
    if (t == 0) rowstart[N] = soff;
}

__global__ void k_scatter(const int* __restrict__ dst, const int* __restrict__ rowstart,
                          int* __restrict__ cursor, int* __restrict__ el, int E) {
    int e = blockIdx.x * 256 + threadIdx.x;
    if (e >= E) return;
    int d = dst[e];
    int pos = atomicAdd(&cursor[d], 1);
    el[rowstart[d] + pos] = e;
}

// ---------------------------------------------------------------------------
// LayerNorm: one wave per row of 128, writes f16 for MFMA consumers
// ---------------------------------------------------------------------------
__global__ __launch_bounds__(256) void k_ln(const float* __restrict__ X, const float* __restrict__ g,
                                            const float* __restrict__ b, _Float16* __restrict__ out, int N) {
    int gw   = (blockIdx.x * 256 + threadIdx.x) >> 6;
    int lane = threadIdx.x & 63;
    if (gw >= N) return;
    const float* x = X + (size_t)gw * D;
    float a0 = x[lane], a1 = x[lane + 64];
    float s = a0 + a1;
#pragma unroll
    for (int m = 1; m < 64; m <<= 1) s += __shfl_xor(s, m);
    float mu = s * (1.0f / 128.0f);
    float d0 = a0 - mu, d1 = a1 - mu;
    float v = d0 * d0 + d1 * d1;
#pragma unroll
    for (int m = 1; m < 64; m <<= 1) v += __shfl_xor(v, m);
    float r = rsqrtf(v * (1.0f / 128.0f) + 1e-5f);
    _Float16* o = out + (size_t)gw * D;
    o[lane]      = (_Float16)(d0 * r * g[lane]      + b[lane]);
    o[lane + 64] = (_Float16)(d1 * r * g[lane + 64] + b[lane + 64]);
}

// ---------------------------------------------------------------------------
// MFMA fragment conventions (gfx950 16x16x32, HW-verified layout):
//   A-frag: lane l holds A[m=l&15][k=(l>>4)*8 + 0..7]   (contig 16B)
//   B-frag: lane l holds B[k=(l>>4)*8+j][n=l&15] -> from Wt[n][k] contig 16B
//   C/D   : col = l&15, row = (l>>4)*4 + reg
//
// Wave->tile mapping (round 13): each wave owns a COLUMN STRIPE x all 64 rows.
// B-fragments are reused across the 4 row-tiles (1 load : 4 MFMAs) and loads
// batch ahead of the MFMA cluster -- fixes the weight-load latency bound
// (old mapping: all waves same cols -> 4x redundant loads, 1 load : 1 MFMA).
// ---------------------------------------------------------------------------

// qkv GEMM: C16[N][384] = A[N][128] @ W[128][384] + bias (f16 out for gathers)
// wave w covers cols [w*96, w*96+96), all 64 rows.
__global__ __launch_bounds__(256) void k_qkv_mfma(
    const _Float16* __restrict__ Hin, const _Float16* __restrict__ Wt, // [384][128]
    const float* __restrict__ bias, _Float16* __restrict__ C, int N)
{
    __shared__ _Float16 Ah[64][136];   // pad 8 f16: row stride 272B -> conflict-free frags
    int t = threadIdx.x;
    int n0 = blockIdx.x * 64;
#pragma unroll
    for (int i = 0; i < 4; ++i) {
        int flat = t + i * 256;
        int r = flat >> 4, c = flat & 15;
        f16x8 v = f16x8_zero();
        if (n0 + r < N) v = *(const f16x8*)&Hin[(size_t)(n0 + r) * D + c * 8];
        *(f16x8*)&Ah[r][c * 8] = v;
    }
    __syncthreads();
    int w = t >> 6, lane = t & 63;
    int lr = lane & 15, lg = lane >> 4;
    f16x8 a1[4][4];
#pragma unroll
    for (int rt = 0; rt < 4; ++rt)
#pragma unroll
        for (int kk = 0; kk < 4; ++kk)
            a1[rt][kk] = *(const f16x8*)&Ah[rt * 16 + lr][kk * 32 + lg * 8];
#pragma unroll 2
    for (int ct = 0; ct < 6; ++ct) {
        int col = w * 96 + ct * 16 + lr;
        f16x8 b[4];
#pragma unroll
        for (int kk = 0; kk < 4; ++kk)
            b[kk] = *(const f16x8*)&Wt[(size_t)col * 128 + kk * 32 + lg * 8];
        float bb = bias[col];
#pragma unroll
        for (int rt = 0; rt < 4; ++rt) {
            f32x4 acc = {0.f, 0.f, 0.f, 0.f};
#pragma unroll
            for (int kk = 0; kk < 4; ++kk)
                acc = __builtin_amdgcn_mfma_f32_16x16x32_f16(a1[rt][kk], b[kk], acc, 0, 0, 0);
#pragma unroll
            for (int i = 0; i < 4; ++i) {
                int row = n0 + rt * 16 + lg * 4 + i;
                if (row < N) C[(size_t)row * 384 + col] = (_Float16)(acc[i] + bb);
            }
        }
    }
}

// res GEMM: Out = resid + Agg @ res_W + bias. block 64 rows, 4 waves
__global__ __launch_bounds__(256) void k_res_mfma(
    const _Float16* __restrict__ Agg, const _Float16* __restrict__ Wt, // [128][128]
    const float* __restrict__ bias, const float* __restrict__ resid,
    float* __restrict__ Out, int N)
{
    __shared__ _Float16 Ah[64][136];
    int t = threadIdx.x;
    int n0 = blockIdx.x * 64;
#pragma unroll
    for (int i = 0; i < 4; ++i) {
        int flat = t + i * 256;
        int r = flat >> 4, c = flat & 15;
        f16x8 v = f16x8_zero();
        if (n0 + r < N) v = *(const f16x8*)&Agg[(size_t)(n0 + r) * D + c * 8];
        *(f16x8*)&Ah[r][c * 8] = v;
    }
    __syncthreads();
    int w = t >> 6, lane = t & 63;
    int rt0 = w * 16, lr = lane & 15, lg = lane >> 4;
    f16x8 a1[4];
#pragma unroll
    for (int kk = 0; kk < 4; ++kk)
        a1[kk] = *(const f16x8*)&Ah[rt0 + lr][kk * 32 + lg * 8];
#pragma unroll
    for (int ct = 0; ct < 8; ++ct) {
        int col = ct * 16 + lr;
        f32x4 acc = {0.f, 0.f, 0.f, 0.f};
#pragma unroll
        for (int kk = 0; kk < 4; ++kk) {
            f16x8 b = *(const f16x8*)&Wt[(size_t)col * 128 + kk * 32 + lg * 8];
            acc = __builtin_amdgcn_mfma_f32_16x16x32_f16(a1[kk], b, acc, 0, 0, 0);
        }
        float bb = bias[col];
#pragma unroll
        for (int i = 0; i < 4; ++i) {
            int row = n0 + rt0 + lg * 4 + i;
            if (row < N) {
                size_t o = (size_t)row * D + col;
                Out[o] = resid[o] + acc[i] + bb;
            }
        }
    }
}

// fused FFN: Out = Xres + gelu(Hin@Win+bin)@Wout+bout. block 64 rows, 4 waves.
// Column-split waves: GEMM1 wave w -> hid cols [w*64,+64) of the 256-chunk;
// GEMM2 wave w -> out cols [w*32,+32). Barriers around the shared hid buffer.
__global__ __launch_bounds__(256) void k_ffn_mfma(
    const _Float16* __restrict__ Hin, const float* __restrict__ Xres,
    const _Float16* __restrict__ Wt1,  // [512][128] (Win^T)
    const float* __restrict__ bin,
    const _Float16* __restrict__ Wt2,  // [128][512] (Wout^T)
    const float* __restrict__ bout,
    float* __restrict__ Out, int N)
{
    __shared__ _Float16 Ah[64][136];
    __shared__ _Float16 hid[64][264];  // 256-col chunk + 8 pad (row stride 528B)
    int t = threadIdx.x;
    int n0 = blockIdx.x * 64;
#pragma unroll
    for (int i = 0; i < 4; ++i) {
        int flat = t + i * 256;
        int r = flat >> 4, c = flat & 15;
        f16x8 v = f16x8_zero();
        if (n0 + r < N) v = *(const f16x8*)&Hin[(size_t)(n0 + r) * D + c * 8];
        *(f16x8*)&Ah[r][c * 8] = v;
    }
    __syncthreads();
    int w = t >> 6, lane = t & 63;
    int lr = lane & 15, lg = lane >> 4;
    f16x8 a1[4][4];
#pragma unroll
    for (int rt = 0; rt < 4; ++rt)
#pragma unroll
        for (int kk = 0; kk < 4; ++kk)
            a1[rt][kk] = *(const f16x8*)&Ah[rt * 16 + lr][kk * 32 + lg * 8];

    f32x4 acc2[2][4];
#pragma unroll
    for (int c = 0; c < 2; ++c)
#pragma unroll
        for (int r = 0; r < 4; ++r) acc2[c][r] = (f32x4){0.f, 0.f, 0.f, 0.f};

    for (int ch = 0; ch < 2; ++ch) {
        // GEMM1: wave's 64-col stripe of this 256-col hidden chunk
#pragma unroll
        for (int ct = 0; ct < 4; ++ct) {
            int colg = ch * 256 + w * 64 + ct * 16 + lr;   // global hidden col
            f16x8 b[4];
#pragma unroll
            for (int kk = 0; kk < 4; ++kk)
                b[kk] = *(const f16x8*)&Wt1[(size_t)colg * 128 + kk * 32 + lg * 8];
            float bb = bin[colg];
#pragma unroll
            for (int rt = 0; rt < 4; ++rt) {
                f32x4 c1 = {0.f, 0.f, 0.f, 0.f};
#pragma unroll
                for (int kk = 0; kk < 4; ++kk)
                    c1 = __builtin_amdgcn_mfma_f32_16x16x32_f16(a1[rt][kk], b[kk], c1, 0, 0, 0);
#pragma unroll
                for (int j = 0; j < 4; ++j)
                    hid[rt * 16 + lg * 4 + j][w * 64 + ct * 16 + lr] = (_Float16)gelu(c1[j] + bb);
            }
        }
        __syncthreads();   // hid complete (all waves' stripes)
        // GEMM2: wave's 32-col out stripe, K-chunk ch
#pragma unroll 2
        for (int kk2 = 0; kk2 < 8; ++kk2) {
            f16x8 a2[4];
#pragma unroll
            for (int rt = 0; rt < 4; ++rt)
                a2[rt] = *(const f16x8*)&hid[rt * 16 + lr][kk2 * 32 + lg * 8];
#pragma unroll
            for (int ct2 = 0; ct2 < 2; ++ct2) {
                int colo = w * 32 + ct2 * 16 + lr;
                f16x8 b2 = *(const f16x8*)&Wt2[(size_t)colo * 512 + ch * 256 + kk2 * 32 + lg * 8];
#pragma unroll
                for (int rt = 0; rt < 4; ++rt)
                    acc2[ct2][rt] = __builtin_amdgcn_mfma_f32_16x16x32_f16(a2[rt], b2, acc2[ct2][rt], 0, 0, 0);
            }
        }
        __syncthreads();   // hid consumed; safe to overwrite next chunk
    }
#pragma unroll
    for (int ct2 = 0; ct2 < 2; ++ct2) {
        int colo = w * 32 + ct2 * 16 + lr;
        float bb = bout[colo];
#pragma unroll
        for (int rt = 0; rt < 4; ++rt)
#pragma unroll
            for (int i = 0; i < 4; ++i) {
                int row = n0 + rt * 16 + lg * 4 + i;
                if (row < N) {
                    size_t o = (size_t)row * D + colo;
                    Out[o] = Xres[o] + acc2[ct2][rt][i] + bb;
                }
            }
    }
}

// ---------------------------------------------------------------------------
// fused attention: per node (wave), single pass over CSR edges.
// lane l owns dims {2l, 2l+1}; head = l>>4 (dh=32 -> 16 lanes per head).
// 4-way edge unroll: 4 independent gather chains in flight (latency-bound fix).
// ---------------------------------------------------------------------------
__global__ __launch_bounds__(256) void k_attn_agg(
    const _Float16* __restrict__ qkv,   // [N][384] f16: q|k|v
    const int* __restrict__ rowstart, const int* __restrict__ el,
    const int* __restrict__ src, const float* __restrict__ base_attn,
    _Float16* __restrict__ agg, int N)
{
    int gw   = (blockIdx.x * 256 + threadIdx.x) >> 6;
    int lane = threadIdx.x & 63;
    if (gw >= N) return;
    int head = lane >> 4;
    f16x2 kk = *(const f16x2*)&qkv[(size_t)gw * 384 + 128 + 2 * lane];
    float k0 = (float)kk[0], k1 = (float)kk[1];
    int beg = rowstart[gw], end = rowstart[gw + 1];
    float s = 0.0f, a0 = 0.0f, a1 = 0.0f;
    int i = beg;
    for (; i + 4 <= end; i += 4) {
        int   e[4], sr[4];
        f16x2 qq[4], vv[4];
        float bb[4], tt[4];
#pragma unroll
        for (int j = 0; j < 4; ++j) e[j] = el[i + j];
#pragma unroll
        for (int j = 0; j < 4; ++j) sr[j] = src[e[j]];
#pragma unroll
        for (int j = 0; j < 4; ++j) {
            const _Float16* row = qkv + (size_t)sr[j] * 384;
            qq[j] = *(const f16x2*)&row[2 * lane];
            vv[j] = *(const f16x2*)&row[256 + 2 * lane];
            bb[j] = base_attn[(size_t)e[j] * 4 + head];
        }
#pragma unroll
        for (int j = 0; j < 4; ++j)
            tt[j] = (float)qq[j][0] * k0 + (float)qq[j][1] * k1;
#pragma unroll
        for (int m = 1; m <= 8; m <<= 1) {
#pragma unroll
            for (int j = 0; j < 4; ++j) tt[j] += __shfl_xor(tt[j], m);
        }
#pragma unroll
        for (int j = 0; j < 4; ++j) {
            float ex = expf(tt[j] * SCALE + bb[j]);
            s  += ex;
            a0 += ex * (float)vv[j][0];
            a1 += ex * (float)vv[j][1];
        }
    }
    for (; i < end; ++i) {
        int e  = el[i];
        int sr = src[e];
        const _Float16* row = qkv + (size_t)sr * 384;
        f16x2 qq = *(const f16x2*)&row[2 * lane];
        float t = (float)qq[0] * k0 + (float)qq[1] * k1;
#pragma unroll
        for (int m = 1; m <= 8; m <<= 1) t += __shfl_xor(t, m);
        float ex = expf(t * SCALE + base_attn[(size_t)e * 4 + head]);
        f16x2 vv = *(const f16x2*)&row[256 + 2 * lane];
        s  += ex;
        a0 += ex * (float)vv[0];
        a1 += ex * (float)vv[1];
    }
    float inv = (s > 0.0f) ? 1.0f / s : 0.0f;
    f16x2 o;
    o[0] = (_Float16)(a0 * inv);
    o[1] = (_Float16)(a1 * inv);
    *(f16x2*)&agg[(size_t)gw * D + 2 * lane] = o;
}

// ---------------------------------------------------------------------------
extern "C" void kernel_launch(void* const* d_in, const int* in_sizes, int n_in,
                              void* d_out, int out_size, void* d_ws, size_t ws_size,
                              hipStream_t stream) {
    const float* triplet_h = (const float*)d_in[0];
    const float* ple    = (const float*)d_in[1];
    const float* vpe    = (const float*)d_in[2];
    const float* sle    = (const float*)d_in[3];
    const float* dW1    = (const float*)d_in[4];
    const float* db1    = (const float*)d_in[5];
    const float* dW2    = (const float*)d_in[6];
    const float* db2    = (const float*)d_in[7];
    const float* tWin   = (const float*)d_in[8];
    const float* tbin   = (const float*)d_in[9];
    const float* tWout  = (const float*)d_in[10];
    const float* tbout  = (const float*)d_in[11];
    const float* pW1    = (const float*)d_in[12];
    const float* pb1    = (const float*)d_in[13];
    const float* pW2    = (const float*)d_in[14];
    const float* pb2    = (const float*)d_in[15];
    const float* ln1_g  = (const float*)d_in[16];
    const float* ln1_b  = (const float*)d_in[17];
    const float* qkv_W  = (const float*)d_in[18];
    const float* qkv_b  = (const float*)d_in[19];
    const float* rln_g  = (const float*)d_in[20];
    const float* rln_b  = (const float*)d_in[21];
    const float* res_W  = (const float*)d_in[22];
    const float* res_b  = (const float*)d_in[23];
    const float* fWin   = (const float*)d_in[24];
    const float* fbin   = (const float*)d_in[25];
    const float* fWout  = (const float*)d_in[26];
    const float* fbout  = (const float*)d_in[27];
    const int*   srcp   = (const int*)d_in[28];
    const int*   dstp   = (const int*)d_in[29];
    const int*   path   = (const int*)d_in[30];
    const int*   vp     = (const int*)d_in[31];
    const int*   sl     = (const int*)d_in[32];

    const int N = in_sizes[0] / D;
    const int E = in_sizes[28];

    char* ws = (char*)d_ws;
    size_t off = 0;
    auto alloc = [&](size_t bytes) -> void* {
        void* p = ws + off;
        off += (bytes + 255) & ~(size_t)255;
        return p;
    };
    float*     tab      = (float*)alloc((size_t)PP * N * DT * 4);
    float*     dist_tab = (float*)alloc(8 * H * 4);
    float*     base_attn= (float*)alloc((size_t)E * H * 4);
    int*       deg      = (int*)alloc((size_t)N * 4);
    int*       rowstart = (int*)alloc((size_t)(N + 1) * 4);
    int*       cursor   = (int*)alloc((size_t)N * 4);
    int*       el       = (int*)alloc((size_t)E * 4);
    _Float16*  hbuf     = (_Float16*)alloc((size_t)N * D * 2);
    _Float16*  qkvbuf   = (_Float16*)alloc((size_t)N * 384 * 2);
    _Float16*  aggbuf   = (_Float16*)alloc((size_t)N * D * 2);
    float*     bufA     = (float*)alloc((size_t)N * D * 4);
    float*     bufB     = (float*)alloc((size_t)N * D * 4);
    _Float16*  WtQ      = (_Float16*)alloc((size_t)NL * 384 * 128 * 2);
    _Float16*  WtR      = (_Float16*)alloc((size_t)NL * 128 * 128 * 2);
    _Float16*  Wt1      = (_Float16*)alloc((size_t)NL * 512 * 128 * 2);
    _Float16*  Wt2      = (_Float16*)alloc((size_t)NL * 128 * 512 * 2);
    _Float16*  WtTin    = (_Float16*)alloc((size_t)PP * DT * 128 * 2);
    _Float16*  WtTout   = (_Float16*)alloc((size_t)PP * DT * DT * 2);
    if (off > ws_size) return;

    hipMemsetAsync(deg,    0, (size_t)N * 4, stream);
    hipMemsetAsync(cursor, 0, (size_t)N * 4, stream);

    // weight transpose-convert (f32 [K][C] -> f16 [C][K])
    WPrep wp;
    wp.src[0] = qkv_W;                wp.dst[0] = WtQ;               wp.K[0] = 128; wp.C[0] = 384;
    wp.src[1] = qkv_W + 128 * 384;    wp.dst[1] = WtQ + 384 * 128;   wp.K[1] = 128; wp.C[1] = 384;
    wp.src[2] = res_W;                wp.dst[2] = WtR;               wp.K[2] = 128; wp.C[2] = 128;
    wp.src[3] = res_W + 128 * 128;    wp.dst[3] = WtR + 128 * 128;   wp.K[3] = 128; wp.C[3] = 128;
    wp.src[4] = fWin;                 wp.dst[4] = Wt1;               wp.K[4] = 128; wp.C[4] = 512;
    wp.src[5] = fWin + 128 * 512;     wp.dst[5] = Wt1 + 512 * 128;   wp.K[5] = 128; wp.C[5] = 512;
    wp.src[6] = fWout;                wp.dst[6] = Wt2;               wp.K[6] = 512; wp.C[6] = 128;
    wp.src[7] = fWout + 512 * 128;    wp.dst[7] = Wt2 + 128 * 512;   wp.K[7] = 512; wp.C[7] = 128;
    for (int i = 0; i < PP; ++i) {
        wp.src[8 + i]  = tWin  + (size_t)i * 128 * DT;
        wp.dst[8 + i]  = WtTin + (size_t)i * DT * 128;
        wp.K[8 + i] = 128; wp.C[8 + i] = DT;
        wp.src[13 + i] = tWout  + (size_t)i * DT * DT;
        wp.dst[13 + i] = WtTout + (size_t)i * DT * DT;
        wp.K[13 + i] = DT; wp.C[13 + i] = DT;
    }
    k_wprep<<<dim3(256, NWP), 256, 0, stream>>>(wp);

    k_dist_tab<<<1, 256, 0, stream>>>(ple, vpe, sle, dW1, db1, dW2, db2, dist_tab);
    k_tab_mfma<<<(N + 63) / 64, 256, 0, stream>>>(triplet_h, WtTin, tbin, WtTout, tbout, tab, N);
    k_edge_pre<<<(E + 255) / 256, 256, 0, stream>>>(path, vp, sl, tab, dist_tab,
                                                    pW1, pb1, pW2, pb2, base_attn, E, N);
    k_count<<<(E + 255) / 256, 256, 0, stream>>>(dstp, deg, E);
    k_scan<<<1, 1024, 0, stream>>>(deg, rowstart, N);
    k_scatter<<<(E + 255) / 256, 256, 0, stream>>>(dstp, rowstart, cursor, el, E);

    hipMemcpyAsync(bufA, triplet_h, (size_t)N * D * 4, hipMemcpyDeviceToDevice, stream);

    for (int l = 0; l < NL; ++l) {
        k_ln<<<(N + 3) / 4, 256, 0, stream>>>(bufA, ln1_g + l * D, ln1_b + l * D, hbuf, N);
        k_qkv_mfma<<<(N + 63) / 64, 256, 0, stream>>>(hbuf, WtQ + (size_t)l * 384 * 128,
                                                      qkv_b + l * 384, qkvbuf, N);
        k_attn_agg<<<(N + 3) / 4, 256, 0, stream>>>(qkvbuf, rowstart, el, srcp,
                                                    base_attn, aggbuf, N);
        k_res_mfma<<<(N + 63) / 64, 256, 0, stream>>>(aggbuf, WtR + (size_t)l * 128 * 128,
                                                      res_b + l * D, bufA, bufB, N);
        k_ln<<<(N + 3) / 4, 256, 0, stream>>>(bufB, rln_g + l * D, rln_b + l * D, hbuf, N);
        k_ffn_mfma<<<(N + 63) / 64, 256, 0, stream>>>(hbuf, bufB,
                                                      Wt1 + (size_t)l * 512 * 128, fbin + l * FF,
                                                      Wt2 + (size_t)l * 128 * 512, fbout + l * D,
                                                      bufA, N);
    }

    hipMemcpyAsync(d_out, bufA, (size_t)N * D * 4, hipMemcpyDeviceToDevice, stream);
}